// Round 2
// baseline (155.827 us; speedup 1.0000x reference)
//
#include <hip/hip_runtime.h>
#include <hip/hip_bf16.h>

#define B_ 8
#define N_ 1024
#define FIN_ 256
#define H_ 8
#define F_ 64
#define HF_ 512
#define BN_ 8192

using bf16x8 = __attribute__((ext_vector_type(8))) short;
using f32x4  = __attribute__((ext_vector_type(4))) float;
using i32x4  = __attribute__((ext_vector_type(4))) int;

__device__ __forceinline__ short f2bf(float x) {
  __hip_bfloat16 b = __float2bfloat16(x);   // compiler lowers to HW cvt on gfx950
  return *reinterpret_cast<short*>(&b);
}

// K0: Wt[f][c] = bf16(W[c][f]) (blocks 1024..1535) and xb = bf16(x) (blocks 0..1023)
__global__ __launch_bounds__(256) void k_cvt(
    const float* __restrict__ x, const float* __restrict__ W,
    short* __restrict__ xb, short* __restrict__ Wt) {
  const int bid = blockIdx.x;
  if (bid < 1024) {
    const int idx = (bid * 256 + threadIdx.x) * 8;  // 1024*256*8 = 2,097,152 = B*N*FIN
    f32x4 a = *(const f32x4*)(x + idx);
    f32x4 b = *(const f32x4*)(x + idx + 4);
    bf16x8 o;
    o[0]=f2bf(a[0]); o[1]=f2bf(a[1]); o[2]=f2bf(a[2]); o[3]=f2bf(a[3]);
    o[4]=f2bf(b[0]); o[5]=f2bf(b[1]); o[6]=f2bf(b[2]); o[7]=f2bf(b[3]);
    *(bf16x8*)(xb + idx) = o;
  } else {
    const int idx = (bid - 1024) * 256 + threadIdx.x;  // 512*256 = 131072 = HF*FIN
    const int f = idx >> 8, c = idx & 255;
    Wt[f * FIN_ + c] = f2bf(W[c * HF_ + f]);
  }
}

// K1: h_t = (x@W)^T bf16 [512][8192]; fused el_t/er_t [8][8192] f32.
__global__ __launch_bounds__(256) void k_h(
    const short* __restrict__ Wt, const short* __restrict__ xb,
    const float* __restrict__ aL, const float* __restrict__ aR,
    short* __restrict__ h_t, float* __restrict__ el_t, float* __restrict__ er_t) {
  const int nt = blockIdx.x;       // 128 n-tiles of 64
  const int h  = blockIdx.y;       // 8 heads
  const int w  = threadIdx.x >> 6;
  const int l  = threadIdx.x & 63;
  const int lr = l & 15, lk = l >> 4;
  const int n0 = nt * 64;
  const int fbase = h * 64 + w * 16;

  f32x4 acc[4] = {};
  const short* arow = Wt + (fbase + lr) * FIN_ + lk * 8;

#pragma unroll
  for (int k0 = 0; k0 < FIN_; k0 += 32) {
    bf16x8 a = *(const bf16x8*)(arow + k0);
#pragma unroll
    for (int nf = 0; nf < 4; nf++) {
      bf16x8 bb = *(const bf16x8*)(xb + (size_t)(n0 + nf * 16 + lr) * FIN_ + k0 + lk * 8);
      acc[nf] = __builtin_amdgcn_mfma_f32_16x16x32_bf16(a, bb, acc[nf], 0, 0, 0);
    }
  }

  __shared__ float sEl[4][64], sEr[4][64];
  float al[4], ar[4];
#pragma unroll
  for (int r = 0; r < 4; r++) {
    const int fl = w * 16 + lk * 4 + r;
    al[r] = aL[h * F_ + fl];
    ar[r] = aR[h * F_ + fl];
  }
#pragma unroll
  for (int nf = 0; nf < 4; nf++) {
    const int n = n0 + nf * 16 + lr;
#pragma unroll
    for (int r = 0; r < 4; r++)
      h_t[(size_t)(fbase + lk * 4 + r) * BN_ + n] = f2bf(acc[nf][r]);
    float pl = acc[nf][0]*al[0] + acc[nf][1]*al[1] + acc[nf][2]*al[2] + acc[nf][3]*al[3];
    float pr = acc[nf][0]*ar[0] + acc[nf][1]*ar[1] + acc[nf][2]*ar[2] + acc[nf][3]*ar[3];
    pl += __shfl_xor(pl, 16); pl += __shfl_xor(pl, 32);
    pr += __shfl_xor(pr, 16); pr += __shfl_xor(pr, 32);
    if (lk == 0) { sEl[w][nf * 16 + lr] = pl; sEr[w][nf * 16 + lr] = pr; }
  }
  __syncthreads();
  if (threadIdx.x < 64) {
    const int n = threadIdx.x;
    el_t[h * BN_ + n0 + n] = sEl[0][n] + sEl[1][n] + sEl[2][n] + sEl[3][n];
    er_t[h * BN_ + n0 + n] = sEr[0][n] + sEr[1][n] + sEr[2][n] + sEr[3][n];
  }
}

// K2: fused attention, no online rescale (logits bounded; softmax shift-invariant).
// Block = (b, 16-row i-tile), wave = head. 512 blocks x 8 waves = 16 waves/CU.
struct EBuf { f32x4 er0, er1, p0, p1; i32x4 k0, k1; };

__device__ __forceinline__ EBuf ldE(const float* erp, const float* pp, const int* mp, int j) {
  EBuf b;
  const int o = j * 32;
  b.er0 = *(const f32x4*)(erp + o);
  b.er1 = *(const f32x4*)(erp + o + 4);
  b.p0  = *(const f32x4*)(pp + o);
  b.p1  = *(const f32x4*)(pp + o + 4);
  b.k0  = *(const i32x4*)(mp + o);
  b.k1  = *(const i32x4*)(mp + o + 4);
  return b;
}

__device__ __forceinline__ void stepf(const EBuf& c, const short* hp, int j,
                                      float el, float es, f32x4 acc[4], f32x4& accS,
                                      bf16x8 ones) {
  const int o = j * 32;
  bf16x8 h0 = *(const bf16x8*)(hp + o);
  bf16x8 h1 = *(const bf16x8*)(hp + o + (size_t)16 * BN_);
  bf16x8 h2 = *(const bf16x8*)(hp + o + (size_t)32 * BN_);
  bf16x8 h3 = *(const bf16x8*)(hp + o + (size_t)48 * BN_);
  float pe[8];
#pragma unroll
  for (int t = 0; t < 4; t++) {
    float s = el + c.er0[t];
    s = fmaxf(s, 0.2f * s);              // leaky-relu
    s = fmaf(es, c.p0[t], s);
    float p = __expf(s);
    pe[t] = (c.k0[t] != 0) ? p : 0.f;
    float s2 = el + c.er1[t];
    s2 = fmaxf(s2, 0.2f * s2);
    s2 = fmaf(es, c.p1[t], s2);
    float p2 = __expf(s2);
    pe[t + 4] = (c.k1[t] != 0) ? p2 : 0.f;
  }
  bf16x8 pf;
#pragma unroll
  for (int t = 0; t < 8; t++) pf[t] = f2bf(pe[t]);
  accS   = __builtin_amdgcn_mfma_f32_16x16x32_bf16(ones, pf, accS, 0, 0, 0);
  acc[0] = __builtin_amdgcn_mfma_f32_16x16x32_bf16(h0, pf, acc[0], 0, 0, 0);
  acc[1] = __builtin_amdgcn_mfma_f32_16x16x32_bf16(h1, pf, acc[1], 0, 0, 0);
  acc[2] = __builtin_amdgcn_mfma_f32_16x16x32_bf16(h2, pf, acc[2], 0, 0, 0);
  acc[3] = __builtin_amdgcn_mfma_f32_16x16x32_bf16(h3, pf, acc[3], 0, 0, 0);
}

__global__ __launch_bounds__(512, 4) void k_attn(
    const short* __restrict__ h_t, const float* __restrict__ el_t,
    const float* __restrict__ er_t, const float* __restrict__ prior,
    const int* __restrict__ mask, const float* __restrict__ esp,
    float* __restrict__ out) {
  const int b  = blockIdx.x >> 6;
  const int it = blockIdx.x & 63;
  const int h  = threadIdx.x >> 6;
  const int l  = threadIdx.x & 63;
  const int lr = l & 15, lk = l >> 4;
  const float es = *esp;
  const int i0 = it * 16;
  const size_t bn = (size_t)b * N_;

  const float el = el_t[h * BN_ + bn + i0 + lr];
  const float* erp = er_t + h * BN_ + bn + lk * 8;
  const float* pp  = prior + ((size_t)b * N_ + i0 + lr) * N_ + lk * 8;
  const int*   mp  = mask  + ((size_t)b * N_ + i0 + lr) * N_ + lk * 8;
  const short* hp  = h_t + (size_t)(h * 64 + lr) * BN_ + bn + lk * 8;

  bf16x8 ones;
#pragma unroll
  for (int t = 0; t < 8; t++) ones[t] = (short)0x3F80;  // bf16 1.0

  f32x4 acc[4] = {};
  f32x4 accS = {};

  EBuf cur = ldE(erp, pp, mp, 0);
  for (int j = 0; j < 31; ++j) {
    EBuf nxt = ldE(erp, pp, mp, j + 1);   // prefetch next 32-j window
    stepf(cur, hp, j, el, es, acc, accS, ones);
    cur = nxt;
  }
  stepf(cur, hp, 31, el, es, acc, accS, ones);

  const float inv = 1.0f / accS[0];       // ones-row MFMA = exact bf16 row-sum
  const size_t row = bn + i0 + lr;
#pragma unroll
  for (int ff = 0; ff < 4; ff++) {
    f32x4 v = acc[ff];
    v[0] *= inv; v[1] *= inv; v[2] *= inv; v[3] *= inv;
    *(f32x4*)(out + row * HF_ + h * 64 + ff * 16 + lk * 4) = v;
  }
}

extern "C" void kernel_launch(void* const* d_in, const int* in_sizes, int n_in,
                              void* d_out, int out_size, void* d_ws, size_t ws_size,
                              hipStream_t stream) {
  const float* x     = (const float*)d_in[0];
  const int*   adj   = (const int*)  d_in[1];
  const float* prior = (const float*)d_in[2];
  const float* W     = (const float*)d_in[3];
  const float* aL    = (const float*)d_in[4];
  const float* aR    = (const float*)d_in[5];
  const float* es    = (const float*)d_in[6];
  float* out = (float*)d_out;

  char* ws = (char*)d_ws;
  short* h_t  = (short*)ws;                                    // 8 MB
  short* xb   = (short*)(ws + 8u * 1024 * 1024);               // 4 MB
  short* Wt   = (short*)(ws + 12u * 1024 * 1024);              // 256 KB
  float* el_t = (float*)(ws + 12u * 1024 * 1024 + 256 * 1024); // 256 KB
  float* er_t = (float*)(ws + 12u * 1024 * 1024 + 512 * 1024); // 256 KB

  hipLaunchKernelGGL(k_cvt, dim3(1536), dim3(256), 0, stream, x, W, xb, Wt);
  hipLaunchKernelGGL(k_h, dim3(128, 8), dim3(256), 0, stream,
                     Wt, xb, aL, aR, h_t, el_t, er_t);
  hipLaunchKernelGGL(k_attn, dim3(512), dim3(512), 0, stream,
                     h_t, el_t, er_t, prior, adj, es, out);
}

// Round 3
// 79.220 us; speedup vs baseline: 1.9670x; 1.9670x over previous
//
#include <hip/hip_runtime.h>
#include <hip/hip_bf16.h>

#define B_ 8
#define N_ 1024
#define FIN_ 256
#define H_ 8
#define F_ 64
#define HF_ 512
#define BN_ 8192
#define LOG2E 1.4426950408889634f

using bf16x8 = __attribute__((ext_vector_type(8))) short;
using f32x4  = __attribute__((ext_vector_type(4))) float;
using i32x4  = __attribute__((ext_vector_type(4))) int;

__device__ __forceinline__ short f2bf(float x) {
  __hip_bfloat16 b = __float2bfloat16(x);
  return *reinterpret_cast<short*>(&b);
}
__device__ __forceinline__ float bf2f(short s) {
  union { unsigned u; float f; } v;
  v.u = ((unsigned)(unsigned short)s) << 16;
  return v.f;
}

// K0: xb = bf16(x) (blocks 0..1023); Wt[f][c] = bf16(W[c][f]) (blocks 1024..1535)
__global__ __launch_bounds__(256) void k_cvt(
    const float* __restrict__ x, const float* __restrict__ W,
    short* __restrict__ xb, short* __restrict__ Wt) {
  const int bid = blockIdx.x;
  if (bid < 1024) {
    const int idx = (bid * 256 + threadIdx.x) * 8;
    f32x4 a = *(const f32x4*)(x + idx);
    f32x4 b = *(const f32x4*)(x + idx + 4);
    bf16x8 o;
    o[0]=f2bf(a[0]); o[1]=f2bf(a[1]); o[2]=f2bf(a[2]); o[3]=f2bf(a[3]);
    o[4]=f2bf(b[0]); o[5]=f2bf(b[1]); o[6]=f2bf(b[2]); o[7]=f2bf(b[3]);
    *(bf16x8*)(xb + idx) = o;
  } else {
    const int idx = (bid - 1024) * 256 + threadIdx.x;
    const int f = idx >> 8, c = idx & 255;
    Wt[f * FIN_ + c] = f2bf(W[c * HF_ + f]);
  }
}

// K_pre: cmat[b][i][j] = bf16( mask ? es*log2e*prior : -1e30 )
__global__ __launch_bounds__(256) void k_pre(
    const float* __restrict__ prior, const int* __restrict__ mask,
    const float* __restrict__ esp, short* __restrict__ cmat) {
  const float es = esp[0] * LOG2E;
  const size_t idx = ((size_t)blockIdx.x * 256 + threadIdx.x) * 8;  // 8M elems /8
  f32x4 p0 = *(const f32x4*)(prior + idx);
  f32x4 p1 = *(const f32x4*)(prior + idx + 4);
  i32x4 m0 = *(const i32x4*)(mask + idx);
  i32x4 m1 = *(const i32x4*)(mask + idx + 4);
  bf16x8 o;
#pragma unroll
  for (int e = 0; e < 4; e++) {
    o[e]     = f2bf(m0[e] != 0 ? es * p0[e] : -1e30f);
    o[e + 4] = f2bf(m1[e] != 0 ? es * p1[e] : -1e30f);
  }
  *(bf16x8*)(cmat + idx) = o;
}

// K1: h_t = (x@W)^T bf16 [512][8192]; el_t/er_t [8][8192] f32 (pre-scaled by log2e).
__global__ __launch_bounds__(256) void k_h(
    const short* __restrict__ Wt, const short* __restrict__ xb,
    const float* __restrict__ aL, const float* __restrict__ aR,
    short* __restrict__ h_t, float* __restrict__ el_t, float* __restrict__ er_t) {
  const int nt = blockIdx.x;
  const int h  = blockIdx.y;
  const int w  = threadIdx.x >> 6;
  const int l  = threadIdx.x & 63;
  const int lr = l & 15, lk = l >> 4;
  const int n0 = nt * 64;
  const int fbase = h * 64 + w * 16;

  f32x4 acc[4] = {};
  const short* arow = Wt + (fbase + lr) * FIN_ + lk * 8;

#pragma unroll
  for (int k0 = 0; k0 < FIN_; k0 += 32) {
    bf16x8 a = *(const bf16x8*)(arow + k0);
#pragma unroll
    for (int nf = 0; nf < 4; nf++) {
      bf16x8 bb = *(const bf16x8*)(xb + (size_t)(n0 + nf * 16 + lr) * FIN_ + k0 + lk * 8);
      acc[nf] = __builtin_amdgcn_mfma_f32_16x16x32_bf16(a, bb, acc[nf], 0, 0, 0);
    }
  }

  __shared__ float sEl[4][64], sEr[4][64];
  float al[4], ar[4];
#pragma unroll
  for (int r = 0; r < 4; r++) {
    const int fl = w * 16 + lk * 4 + r;
    al[r] = aL[h * F_ + fl];
    ar[r] = aR[h * F_ + fl];
  }
#pragma unroll
  for (int nf = 0; nf < 4; nf++) {
    const int n = n0 + nf * 16 + lr;
#pragma unroll
    for (int r = 0; r < 4; r++)
      h_t[(size_t)(fbase + lk * 4 + r) * BN_ + n] = f2bf(acc[nf][r]);
    float pl = acc[nf][0]*al[0] + acc[nf][1]*al[1] + acc[nf][2]*al[2] + acc[nf][3]*al[3];
    float pr = acc[nf][0]*ar[0] + acc[nf][1]*ar[1] + acc[nf][2]*ar[2] + acc[nf][3]*ar[3];
    pl += __shfl_xor(pl, 16); pl += __shfl_xor(pl, 32);
    pr += __shfl_xor(pr, 16); pr += __shfl_xor(pr, 32);
    if (lk == 0) { sEl[w][nf * 16 + lr] = pl; sEr[w][nf * 16 + lr] = pr; }
  }
  __syncthreads();
  if (threadIdx.x < 64) {
    const int n = threadIdx.x;
    el_t[h * BN_ + n0 + n] = (sEl[0][n] + sEl[1][n] + sEl[2][n] + sEl[3][n]) * LOG2E;
    er_t[h * BN_ + n0 + n] = (sEr[0][n] + sEr[1][n] + sEr[2][n] + sEr[3][n]) * LOG2E;
  }
}

// K_rep: hA[((bh*32+js)*4+ff)*64 + l][8] = h_t[h*64+ff*16+(l&15)][b*1024+js*32+(l>>4)*8 ..+7]
__global__ __launch_bounds__(256) void k_rep(
    const short* __restrict__ h_t, short* __restrict__ hA) {
  const size_t T = (size_t)blockIdx.x * 256 + threadIdx.x;  // 524288
  const int l  = T & 63;
  const int ff = (T >> 6) & 3;
  const int js = (T >> 8) & 31;
  const int bh = (int)(T >> 13);
  const int b = bh >> 3, h = bh & 7;
  const int f = h * 64 + ff * 16 + (l & 15);
  const int col = b * 1024 + js * 32 + (l >> 4) * 8;
  bf16x8 v = *(const bf16x8*)(h_t + (size_t)f * BN_ + col);
  *(bf16x8*)(hA + T * 8) = v;
}

// K2: fused attention. Block=(b, 16-row i-tile), wave=head.
// c staged in LDS (XOR-swizzled slots), h from fragment-packed hA (lane-linear).
__global__ __launch_bounds__(512, 4) void k_attn(
    const short* __restrict__ hA, const float* __restrict__ el_t,
    const float* __restrict__ er_t, const short* __restrict__ cmat,
    float* __restrict__ out) {
  const int b  = blockIdx.x >> 6;
  const int it = blockIdx.x & 63;
  const int t  = threadIdx.x;
  const int h  = t >> 6;
  const int l  = t & 63;
  const int lr = l & 15, lk = l >> 4;
  const int i0 = it * 16;
  const size_t bn = (size_t)b * N_;

  __shared__ short cbuf[2][4096];

  const float el = el_t[h * BN_ + bn + i0 + lr];
  const float* erp = er_t + h * BN_ + bn + lk * 8;
  const short* hW  = hA + (size_t)(b * 8 + h) * 65536 + l * 8;
  const int rr = t >> 5, sl = t & 31;
  const short* cg = cmat + (bn + i0 + rr) * (size_t)N_ + ((sl ^ (rr & 7)) * 8);

  // stage chunk 0 (write LDS slot linear in t; XOR permutation folded into global col)
  bf16x8 stg0 = *(const bf16x8*)(cg);
  *(bf16x8*)(&cbuf[0][0] + t * 8) = stg0;
  bf16x8 hN[4];
#pragma unroll
  for (int ff = 0; ff < 4; ff++) hN[ff] = *(const bf16x8*)(hW + ff * 512);
  __syncthreads();

  f32x4 acc[4] = {};
  f32x4 accS = {};
  bf16x8 ones;
#pragma unroll
  for (int e = 0; e < 8; e++) ones[e] = (short)0x3F80;  // bf16 1.0

  for (int ch = 0; ch < 4; ++ch) {
    bf16x8 stgN;
    if (ch < 3) stgN = *(const bf16x8*)(cg + (ch + 1) * 256);  // issue early (T14)
    const short* cb = &cbuf[ch & 1][0];
#pragma unroll
    for (int js = 0; js < 8; ++js) {
      const int s = ch * 8 + js;
      bf16x8 h0 = hN[0], h1 = hN[1], h2 = hN[2], h3 = hN[3];
      const int sn = (s < 31) ? s + 1 : 31;
      const short* hs = hW + (size_t)sn * 2048;
      hN[0] = *(const bf16x8*)(hs);
      hN[1] = *(const bf16x8*)(hs + 512);
      hN[2] = *(const bf16x8*)(hs + 1024);
      hN[3] = *(const bf16x8*)(hs + 1536);
      f32x4 er0 = *(const f32x4*)(erp + s * 32);
      f32x4 er1 = *(const f32x4*)(erp + s * 32 + 4);
      bf16x8 cf = *(const bf16x8*)(cb + lr * 256 + (((js * 4 + lk) ^ (lr & 7)) * 8));
      float pe[8];
#pragma unroll
      for (int q = 0; q < 4; q++) {
        float sA = el + er0[q];
        sA = fmaxf(sA, 0.2f * sA);
        sA += bf2f(cf[q]);
        asm("v_exp_f32 %0, %1" : "=v"(pe[q]) : "v"(sA));       // 2^x; masked -> 0
        float sB = el + er1[q];
        sB = fmaxf(sB, 0.2f * sB);
        sB += bf2f(cf[q + 4]);
        asm("v_exp_f32 %0, %1" : "=v"(pe[q + 4]) : "v"(sB));
      }
      bf16x8 pf;
#pragma unroll
      for (int e = 0; e < 8; e++) pf[e] = f2bf(pe[e]);
      accS   = __builtin_amdgcn_mfma_f32_16x16x32_bf16(ones, pf, accS, 0, 0, 0);
      acc[0] = __builtin_amdgcn_mfma_f32_16x16x32_bf16(h0, pf, acc[0], 0, 0, 0);
      acc[1] = __builtin_amdgcn_mfma_f32_16x16x32_bf16(h1, pf, acc[1], 0, 0, 0);
      acc[2] = __builtin_amdgcn_mfma_f32_16x16x32_bf16(h2, pf, acc[2], 0, 0, 0);
      acc[3] = __builtin_amdgcn_mfma_f32_16x16x32_bf16(h3, pf, acc[3], 0, 0, 0);
    }
    if (ch < 3) {
      __syncthreads();   // all waves done reading buf[(ch+1)&1] (used in chunk ch-1)
      *(bf16x8*)(&cbuf[(ch + 1) & 1][0] + t * 8) = stgN;
      __syncthreads();   // publish
    }
  }

  const float inv = 1.0f / accS[0];
  const size_t row = bn + i0 + lr;
#pragma unroll
  for (int ff = 0; ff < 4; ff++) {
    f32x4 v = acc[ff];
    v[0] *= inv; v[1] *= inv; v[2] *= inv; v[3] *= inv;
    *(f32x4*)(out + row * HF_ + h * 64 + ff * 16 + lk * 4) = v;
  }
}

extern "C" void kernel_launch(void* const* d_in, const int* in_sizes, int n_in,
                              void* d_out, int out_size, void* d_ws, size_t ws_size,
                              hipStream_t stream) {
  const float* x     = (const float*)d_in[0];
  const int*   adj   = (const int*)  d_in[1];
  const float* prior = (const float*)d_in[2];
  const float* W     = (const float*)d_in[3];
  const float* aL    = (const float*)d_in[4];
  const float* aR    = (const float*)d_in[5];
  const float* es    = (const float*)d_in[6];
  float* out = (float*)d_out;

  char* ws = (char*)d_ws;
  short* h_t  = (short*)ws;                                 //  0 MB, 8 MB
  short* hA   = (short*)(ws + 8u  * 1024 * 1024);           //  8 MB, 8 MB
  short* xb   = (short*)(ws + 16u * 1024 * 1024);           // 16 MB, 4 MB
  short* Wt   = (short*)(ws + 20u * 1024 * 1024);           // 20 MB, 256 KB
  float* el_t = (float*)(ws + 20u * 1024 * 1024 + 262144);  // 256 KB
  float* er_t = (float*)(ws + 20u * 1024 * 1024 + 524288);  // 256 KB
  short* cmat = (short*)(ws + 21u * 1024 * 1024);           // 21 MB, 16 MB

  hipLaunchKernelGGL(k_cvt, dim3(1536), dim3(256), 0, stream, x, W, xb, Wt);
  hipLaunchKernelGGL(k_pre, dim3(4096), dim3(256), 0, stream, prior, adj, es, cmat);
  hipLaunchKernelGGL(k_h,   dim3(128, 8), dim3(256), 0, stream,
                     Wt, xb, aL, aR, h_t, el_t, er_t);
  hipLaunchKernelGGL(k_rep, dim3(2048), dim3(256), 0, stream, h_t, hA);
  hipLaunchKernelGGL(k_attn, dim3(512), dim3(512), 0, stream,
                     hA, el_t, er_t, cmat, out);
}

// Round 4
// 75.398 us; speedup vs baseline: 2.0667x; 1.0507x over previous
//
#include <hip/hip_runtime.h>
#include <hip/hip_bf16.h>

#define B_ 8
#define N_ 1024
#define FIN_ 256
#define H_ 8
#define F_ 64
#define HF_ 512
#define BN_ 8192
#define LOG2E 1.4426950408889634f
#define NEG_ 0.2f

using bf16x8 = __attribute__((ext_vector_type(8))) short;
using f32x4  = __attribute__((ext_vector_type(4))) float;
using i32x4  = __attribute__((ext_vector_type(4))) int;

__device__ __forceinline__ short f2bf(float x) {
  __hip_bfloat16 b = __float2bfloat16(x);
  return *reinterpret_cast<short*>(&b);
}
__device__ __forceinline__ float bf2f(short s) {
  union { unsigned u; float f; } v;
  v.u = ((unsigned)(unsigned short)s) << 16;
  return v.f;
}
__device__ __forceinline__ bf16x8 cvtCE(f32x4 pa, f32x4 pb, i32x4 ma, i32x4 mb, float es) {
  bf16x8 o;
#pragma unroll
  for (int e = 0; e < 4; e++) {
    o[e]     = f2bf(ma[e] != 0 ? es * pa[e] : -1e30f);
    o[e + 4] = f2bf(mb[e] != 0 ? es * pb[e] : -1e30f);
  }
  return o;
}

// K0: xb = bf16(x) (blocks 0..1023); Wt[f][c] = bf16(W[c][f]) (blocks 1024..1535)
__global__ __launch_bounds__(256) void k_cvt(
    const float* __restrict__ x, const float* __restrict__ W,
    short* __restrict__ xb, short* __restrict__ Wt) {
  const int bid = blockIdx.x;
  if (bid < 1024) {
    const int idx = (bid * 256 + threadIdx.x) * 8;
    f32x4 a = *(const f32x4*)(x + idx);
    f32x4 b = *(const f32x4*)(x + idx + 4);
    bf16x8 o;
    o[0]=f2bf(a[0]); o[1]=f2bf(a[1]); o[2]=f2bf(a[2]); o[3]=f2bf(a[3]);
    o[4]=f2bf(b[0]); o[5]=f2bf(b[1]); o[6]=f2bf(b[2]); o[7]=f2bf(b[3]);
    *(bf16x8*)(xb + idx) = o;
  } else {
    const int idx = (bid - 1024) * 256 + threadIdx.x;
    const int f = idx >> 8, c = idx & 255;
    Wt[f * FIN_ + c] = f2bf(W[c * HF_ + f]);
  }
}

// K1: h = x@W (per-head 64f x 64n tile), fused el/er epilogue, writes hA in
// MFMA-A-fragment order via LDS transpose: hA[((b8h*32+js)*4+ff)*512 + l*8 + e]
//   = h[f = h*64+ff*16+(l&15)][j = js*32 + (l>>4)*8 + e]   (j local to b)
__global__ __launch_bounds__(256) void k_h(
    const short* __restrict__ Wt, const short* __restrict__ xb,
    const float* __restrict__ aL, const float* __restrict__ aR,
    short* __restrict__ hA, float* __restrict__ el_t, float* __restrict__ er_t) {
  const int nt = blockIdx.x;       // 128 n-tiles of 64 (global n)
  const int h  = blockIdx.y;
  const int w  = threadIdx.x >> 6;
  const int l  = threadIdx.x & 63;
  const int lr = l & 15, lk = l >> 4;
  const int n0 = nt * 64;
  const int fbase = h * 64 + w * 16;

  f32x4 acc[4] = {};
  const short* arow = Wt + (fbase + lr) * FIN_ + lk * 8;

#pragma unroll
  for (int k0 = 0; k0 < FIN_; k0 += 32) {
    bf16x8 a = *(const bf16x8*)(arow + k0);
#pragma unroll
    for (int nf = 0; nf < 4; nf++) {
      bf16x8 bb = *(const bf16x8*)(xb + (size_t)(n0 + nf * 16 + lr) * FIN_ + k0 + lk * 8);
      acc[nf] = __builtin_amdgcn_mfma_f32_16x16x32_bf16(a, bb, acc[nf], 0, 0, 0);
    }
  }

  __shared__ short sT[64][72];     // 72-short rows: 16B-aligned b128 reads, 2-way banks
  __shared__ float sEl[4][64], sEr[4][64];
  float al[4], ar[4];
#pragma unroll
  for (int r = 0; r < 4; r++) {
    const int fl = w * 16 + lk * 4 + r;
    al[r] = aL[h * F_ + fl];
    ar[r] = aR[h * F_ + fl];
  }
#pragma unroll
  for (int nf = 0; nf < 4; nf++) {
    const int nl = nf * 16 + lr;
#pragma unroll
    for (int r = 0; r < 4; r++)
      sT[w * 16 + lk * 4 + r][nl] = f2bf(acc[nf][r]);
    float pl = acc[nf][0]*al[0] + acc[nf][1]*al[1] + acc[nf][2]*al[2] + acc[nf][3]*al[3];
    float pr = acc[nf][0]*ar[0] + acc[nf][1]*ar[1] + acc[nf][2]*ar[2] + acc[nf][3]*ar[3];
    pl += __shfl_xor(pl, 16); pl += __shfl_xor(pl, 32);
    pr += __shfl_xor(pr, 16); pr += __shfl_xor(pr, 32);
    if (lk == 0) { sEl[w][nl] = pl; sEr[w][nl] = pr; }
  }
  __syncthreads();
  if (threadIdx.x < 64) {
    const int n = threadIdx.x;
    el_t[h * BN_ + n0 + n] = (sEl[0][n] + sEl[1][n] + sEl[2][n] + sEl[3][n]) * LOG2E;
    er_t[h * BN_ + n0 + n] = (sEr[0][n] + sEr[1][n] + sEr[2][n] + sEr[3][n]) * LOG2E;
  }
  // fragment-order readback (2 groups of 8 shorts per thread)
  const int b8h = (nt >> 4) * 8 + h;
  const int jb  = (nt & 15) * 2;
#pragma unroll
  for (int gi = 0; gi < 2; gi++) {
    const int g   = threadIdx.x * 2 + gi;   // 0..511
    const int jsl = g >> 8, ff = (g >> 6) & 3, gl = g & 63;
    const int glr = gl & 15, glk = gl >> 4;
    bf16x8 v = *(const bf16x8*)(&sT[ff * 16 + glr][jsl * 32 + glk * 8]);
    *(bf16x8*)(hA + (((size_t)b8h * 32 + jb + jsl) * 4 + ff) * 512 + gl * 8) = v;
  }
}

// K2: fused attention. Block=(b = bid&7 -> XCD-local, 32-row i-tile), wave=head,
// each wave does 2 i-frags sharing h loads. prior/mask streamed+converted into
// XOR-swizzled LDS double-buffer (k_pre fused). No-max softmax, ones-MFMA denom.
__global__ __launch_bounds__(512, 2) void k_attn(
    const short* __restrict__ hA, const float* __restrict__ el_t,
    const float* __restrict__ er_t, const float* __restrict__ prior,
    const int* __restrict__ mask, const float* __restrict__ esp,
    float* __restrict__ out) {
  const int bid = blockIdx.x;
  const int b  = bid & 7;          // XCD = bid % 8 = b
  const int it = bid >> 3;         // 0..31
  const int t  = threadIdx.x;
  const int h  = t >> 6;
  const int l  = t & 63;
  const int lr = l & 15, lk = l >> 4;
  const int i0 = it * 32;
  const size_t bn = (size_t)b * N_;
  const float es = esp[0] * LOG2E;

  __shared__ short cbuf[2][8192];  // 32 rows x 256 j, bf16, XOR-swizzled slots

  const float* elh = el_t + h * BN_ + bn + i0;
  const float el0 = elh[lr], el1 = elh[16 + lr];
  const float* erp = er_t + h * BN_ + bn + lk * 8;
  const short* hW  = hA + (size_t)(b * 8 + h) * 65536 + l * 8;

  // staging geometry: thread covers 2 adjacent global col-groups (64B contiguous)
  const int srow = t >> 4;                  // 0..31
  const int c0   = (t & 15) * 2;
  const int sw   = srow & 7;
  const int gA   = (c0 ^ sw) & ~1;          // even global group base
  const int slotA = (srow * 32 + (gA ^ sw)) * 8;
  const int slotB = (srow * 32 + ((gA | 1) ^ sw)) * 8;
  const size_t grow = (bn + i0 + srow) * (size_t)N_;
  const float* pg = prior + grow + gA * 8;
  const int*   mg = mask  + grow + gA * 8;

  // ---- stage chunk 0 ----
  {
    f32x4 p0 = *(const f32x4*)(pg),     p1 = *(const f32x4*)(pg + 4);
    f32x4 p2 = *(const f32x4*)(pg + 8), p3 = *(const f32x4*)(pg + 12);
    i32x4 m0 = *(const i32x4*)(mg),     m1 = *(const i32x4*)(mg + 4);
    i32x4 m2 = *(const i32x4*)(mg + 8), m3 = *(const i32x4*)(mg + 12);
    *(bf16x8*)(&cbuf[0][slotA]) = cvtCE(p0, p1, m0, m1, es);
    *(bf16x8*)(&cbuf[0][slotB]) = cvtCE(p2, p3, m2, m3, es);
  }
  bf16x8 hN[4];
#pragma unroll
  for (int ff = 0; ff < 4; ff++) hN[ff] = *(const bf16x8*)(hW + ff * 512);
  __syncthreads();

  f32x4 acc[4][2] = {};
  f32x4 accS[2] = {};
  bf16x8 ones;
#pragma unroll
  for (int e = 0; e < 8; e++) ones[e] = (short)0x3F80;

  for (int ch = 0; ch < 4; ++ch) {
    f32x4 p0, p1, p2, p3; i32x4 m0, m1, m2, m3;
    if (ch < 3) {                         // issue next-chunk loads early (T14)
      const int off = (ch + 1) * 256;
      p0 = *(const f32x4*)(pg + off);      p1 = *(const f32x4*)(pg + off + 4);
      p2 = *(const f32x4*)(pg + off + 8);  p3 = *(const f32x4*)(pg + off + 12);
      m0 = *(const i32x4*)(mg + off);      m1 = *(const i32x4*)(mg + off + 4);
      m2 = *(const i32x4*)(mg + off + 8);  m3 = *(const i32x4*)(mg + off + 12);
    }
    const short* cb = cbuf[ch & 1];
#pragma unroll
    for (int js = 0; js < 8; ++js) {
      const int s = ch * 8 + js;
      bf16x8 h0 = hN[0], h1 = hN[1], h2 = hN[2], h3 = hN[3];
      const int sn = (s < 31) ? s + 1 : 31;
      const short* hs = hW + (size_t)sn * 2048;
      hN[0] = *(const bf16x8*)(hs);
      hN[1] = *(const bf16x8*)(hs + 512);
      hN[2] = *(const bf16x8*)(hs + 1024);
      hN[3] = *(const bf16x8*)(hs + 1536);
      f32x4 er0 = *(const f32x4*)(erp + s * 32);
      f32x4 er1 = *(const f32x4*)(erp + s * 32 + 4);
      const int ci = ((js * 4 + lk) ^ (lr & 7)) * 8;
      bf16x8 cA = *(const bf16x8*)(cb + lr * 256 + ci);
      bf16x8 cB = *(const bf16x8*)(cb + (16 + lr) * 256 + ci);
      bf16x8 pfA, pfB;
#pragma unroll
      for (int q = 0; q < 4; q++) {
        const float e0 = er0[q], e1 = er1[q];
        float a1 = el0 + e0; a1 = fmaxf(a1, NEG_ * a1); a1 += bf2f(cA[q]);
        float a2 = el0 + e1; a2 = fmaxf(a2, NEG_ * a2); a2 += bf2f(cA[q + 4]);
        float b1 = el1 + e0; b1 = fmaxf(b1, NEG_ * b1); b1 += bf2f(cB[q]);
        float b2 = el1 + e1; b2 = fmaxf(b2, NEG_ * b2); b2 += bf2f(cB[q + 4]);
        float x1, x2, x3, x4;
        asm("v_exp_f32 %0, %1" : "=v"(x1) : "v"(a1));   // 2^x (log2e pre-folded)
        asm("v_exp_f32 %0, %1" : "=v"(x2) : "v"(a2));
        asm("v_exp_f32 %0, %1" : "=v"(x3) : "v"(b1));
        asm("v_exp_f32 %0, %1" : "=v"(x4) : "v"(b2));
        pfA[q] = f2bf(x1); pfA[q + 4] = f2bf(x2);
        pfB[q] = f2bf(x3); pfB[q + 4] = f2bf(x4);
      }
      accS[0]   = __builtin_amdgcn_mfma_f32_16x16x32_bf16(ones, pfA, accS[0], 0, 0, 0);
      accS[1]   = __builtin_amdgcn_mfma_f32_16x16x32_bf16(ones, pfB, accS[1], 0, 0, 0);
      acc[0][0] = __builtin_amdgcn_mfma_f32_16x16x32_bf16(h0, pfA, acc[0][0], 0, 0, 0);
      acc[0][1] = __builtin_amdgcn_mfma_f32_16x16x32_bf16(h0, pfB, acc[0][1], 0, 0, 0);
      acc[1][0] = __builtin_amdgcn_mfma_f32_16x16x32_bf16(h1, pfA, acc[1][0], 0, 0, 0);
      acc[1][1] = __builtin_amdgcn_mfma_f32_16x16x32_bf16(h1, pfB, acc[1][1], 0, 0, 0);
      acc[2][0] = __builtin_amdgcn_mfma_f32_16x16x32_bf16(h2, pfA, acc[2][0], 0, 0, 0);
      acc[2][1] = __builtin_amdgcn_mfma_f32_16x16x32_bf16(h2, pfB, acc[2][1], 0, 0, 0);
      acc[3][0] = __builtin_amdgcn_mfma_f32_16x16x32_bf16(h3, pfA, acc[3][0], 0, 0, 0);
      acc[3][1] = __builtin_amdgcn_mfma_f32_16x16x32_bf16(h3, pfB, acc[3][1], 0, 0, 0);
    }
    if (ch < 3) {
      short* nb = (short*)cbuf[(ch + 1) & 1];   // not read during this chunk: safe
      *(bf16x8*)(nb + slotA) = cvtCE(p0, p1, m0, m1, es);
      *(bf16x8*)(nb + slotB) = cvtCE(p2, p3, m2, m3, es);
      __syncthreads();                          // publish for next chunk
    }
  }

#pragma unroll
  for (int fi = 0; fi < 2; fi++) {
    const float inv = 1.0f / accS[fi][0];
    const size_t row = bn + i0 + fi * 16 + lr;
#pragma unroll
    for (int ff = 0; ff < 4; ff++) {
      f32x4 v = acc[ff][fi];
      v[0] *= inv; v[1] *= inv; v[2] *= inv; v[3] *= inv;
      *(f32x4*)(out + row * HF_ + h * 64 + ff * 16 + lk * 4) = v;
    }
  }
}

extern "C" void kernel_launch(void* const* d_in, const int* in_sizes, int n_in,
                              void* d_out, int out_size, void* d_ws, size_t ws_size,
                              hipStream_t stream) {
  const float* x     = (const float*)d_in[0];
  const int*   adj   = (const int*)  d_in[1];
  const float* prior = (const float*)d_in[2];
  const float* W     = (const float*)d_in[3];
  const float* aL    = (const float*)d_in[4];
  const float* aR    = (const float*)d_in[5];
  const float* es    = (const float*)d_in[6];
  float* out = (float*)d_out;

  char* ws = (char*)d_ws;
  short* hA   = (short*)ws;                                 //  0 MB, 8 MB
  short* xb   = (short*)(ws + 8u  * 1024 * 1024);           //  8 MB, 4 MB
  short* Wt   = (short*)(ws + 12u * 1024 * 1024);           // 12 MB, 256 KB
  float* el_t = (float*)(ws + 12u * 1024 * 1024 + 262144);  // 256 KB
  float* er_t = (float*)(ws + 12u * 1024 * 1024 + 524288);  // 256 KB

  hipLaunchKernelGGL(k_cvt, dim3(1536), dim3(256), 0, stream, x, W, xb, Wt);
  hipLaunchKernelGGL(k_h,   dim3(128, 8), dim3(256), 0, stream,
                     Wt, xb, aL, aR, hA, el_t, er_t);
  hipLaunchKernelGGL(k_attn, dim3(256), dim3(512), 0, stream,
                     hA, el_t, er_t, prior, adj, es, out);
}

// Round 5
// 70.743 us; speedup vs baseline: 2.2027x; 1.0658x over previous
//
#include <hip/hip_runtime.h>
#include <hip/hip_bf16.h>

#define B_ 8
#define N_ 1024
#define FIN_ 256
#define H_ 8
#define F_ 64
#define HF_ 512
#define BN_ 8192
#define LOG2E 1.4426950408889634f

using bf16x8 = __attribute__((ext_vector_type(8))) short;
using f32x4  = __attribute__((ext_vector_type(4))) float;
using i32x4  = __attribute__((ext_vector_type(4))) int;

__device__ __forceinline__ short f2bf(float x) {
  __hip_bfloat16 b = __float2bfloat16(x);
  return *reinterpret_cast<short*>(&b);
}
__device__ __forceinline__ float bf2f(short s) {
  union { unsigned u; float f; } v;
  v.u = ((unsigned)(unsigned short)s) << 16;
  return v.f;
}
__device__ __forceinline__ bf16x8 cvtCE(f32x4 pa, f32x4 pb, i32x4 ma, i32x4 mb, float es) {
  bf16x8 o;
#pragma unroll
  for (int e = 0; e < 4; e++) {
    o[e]     = f2bf(ma[e] != 0 ? es * pa[e] : -1e30f);
    o[e + 4] = f2bf(mb[e] != 0 ? es * pb[e] : -1e30f);
  }
  return o;
}

// K0: xb = bf16(x) (blocks 0..1023); Wt[f][c] = bf16(W[c][f]) (blocks 1024..1535)
__global__ __launch_bounds__(256) void k_cvt(
    const float* __restrict__ x, const float* __restrict__ W,
    short* __restrict__ xb, short* __restrict__ Wt) {
  const int bid = blockIdx.x;
  if (bid < 1024) {
    const int idx = (bid * 256 + threadIdx.x) * 8;
    f32x4 a = *(const f32x4*)(x + idx);
    f32x4 b = *(const f32x4*)(x + idx + 4);
    bf16x8 o;
    o[0]=f2bf(a[0]); o[1]=f2bf(a[1]); o[2]=f2bf(a[2]); o[3]=f2bf(a[3]);
    o[4]=f2bf(b[0]); o[5]=f2bf(b[1]); o[6]=f2bf(b[2]); o[7]=f2bf(b[3]);
    *(bf16x8*)(xb + idx) = o;
  } else {
    const int idx = (bid - 1024) * 256 + threadIdx.x;
    const int f = idx >> 8, c = idx & 255;
    Wt[f * FIN_ + c] = f2bf(W[c * HF_ + f]);
  }
}

// K1: h = x@W per-head 64f x 64n tile, fused el/er epilogue; writes hA in
// MFMA-A-fragment order via LDS transpose:
// hA[((b8h*32+js)*4+ff)*512 + l*8 + e] = h[h*64+ff*16+(l&15)][js*32+(l>>4)*8+e] (j local to b)
__global__ __launch_bounds__(256) void k_h(
    const short* __restrict__ Wt, const short* __restrict__ xb,
    const float* __restrict__ aL, const float* __restrict__ aR,
    short* __restrict__ hA, float* __restrict__ el_t, float* __restrict__ er_t) {
  const int nt = blockIdx.x;
  const int h  = blockIdx.y;
  const int w  = threadIdx.x >> 6;
  const int l  = threadIdx.x & 63;
  const int lr = l & 15, lk = l >> 4;
  const int n0 = nt * 64;
  const int fbase = h * 64 + w * 16;

  f32x4 acc[4] = {};
  const short* arow = Wt + (fbase + lr) * FIN_ + lk * 8;

#pragma unroll
  for (int k0 = 0; k0 < FIN_; k0 += 32) {
    bf16x8 a = *(const bf16x8*)(arow + k0);
#pragma unroll
    for (int nf = 0; nf < 4; nf++) {
      bf16x8 bb = *(const bf16x8*)(xb + (size_t)(n0 + nf * 16 + lr) * FIN_ + k0 + lk * 8);
      acc[nf] = __builtin_amdgcn_mfma_f32_16x16x32_bf16(a, bb, acc[nf], 0, 0, 0);
    }
  }

  __shared__ short sT[64][72];
  __shared__ float sEl[4][64], sEr[4][64];
  float al[4], ar[4];
#pragma unroll
  for (int r = 0; r < 4; r++) {
    const int fl = w * 16 + lk * 4 + r;
    al[r] = aL[h * F_ + fl];
    ar[r] = aR[h * F_ + fl];
  }
#pragma unroll
  for (int nf = 0; nf < 4; nf++) {
    const int nl = nf * 16 + lr;
#pragma unroll
    for (int r = 0; r < 4; r++)
      sT[w * 16 + lk * 4 + r][nl] = f2bf(acc[nf][r]);
    float pl = acc[nf][0]*al[0] + acc[nf][1]*al[1] + acc[nf][2]*al[2] + acc[nf][3]*al[3];
    float pr = acc[nf][0]*ar[0] + acc[nf][1]*ar[1] + acc[nf][2]*ar[2] + acc[nf][3]*ar[3];
    pl += __shfl_xor(pl, 16); pl += __shfl_xor(pl, 32);
    pr += __shfl_xor(pr, 16); pr += __shfl_xor(pr, 32);
    if (lk == 0) { sEl[w][nl] = pl; sEr[w][nl] = pr; }
  }
  __syncthreads();
  if (threadIdx.x < 64) {
    const int n = threadIdx.x;
    el_t[h * BN_ + n0 + n] = (sEl[0][n] + sEl[1][n] + sEl[2][n] + sEl[3][n]) * LOG2E;
    er_t[h * BN_ + n0 + n] = (sEr[0][n] + sEr[1][n] + sEr[2][n] + sEr[3][n]) * LOG2E;
  }
  const int b8h = (nt >> 4) * 8 + h;
  const int jb  = (nt & 15) * 2;
#pragma unroll
  for (int gi = 0; gi < 2; gi++) {
    const int g   = threadIdx.x * 2 + gi;
    const int jsl = g >> 8, ff = (g >> 6) & 3, gl = g & 63;
    const int glr = gl & 15, glk = gl >> 4;
    bf16x8 v = *(const bf16x8*)(&sT[ff * 16 + glr][jsl * 32 + glk * 8]);
    *(bf16x8*)(hA + (((size_t)b8h * 32 + jb + jsl) * 4 + ff) * 512 + gl * 8) = v;
  }
}

// K2: fused attention. Block = (b = bid&7 -> XCD, 16-row i-tile), wave = head.
// Full c-row (16x1024 bf16 = 32KB) staged in LDS once, ONE barrier, then 32
// register-pipelined j-steps with no further syncs. No-max softmax (logits
// bounded), denominator via ones-row MFMA.
__global__ __launch_bounds__(512, 4) void k_attn(
    const short* __restrict__ hA, const float* __restrict__ el_t,
    const float* __restrict__ er_t, const float* __restrict__ prior,
    const int* __restrict__ mask, const float* __restrict__ esp,
    float* __restrict__ out) {
  const int bid = blockIdx.x;
  const int b  = bid & 7;          // XCD = bid % 8
  const int it = bid >> 3;         // 0..63
  const int t  = threadIdx.x;
  const int h  = t >> 6;
  const int l  = t & 63;
  const int lr = l & 15, lk = l >> 4;
  const int i0 = it * 16;
  const size_t bn = (size_t)b * N_;
  const float es = esp[0] * LOG2E;

  __shared__ short cbuf[16 * 1024];   // 32 KB: c[i-row][j] bf16, XOR-swizzled groups

  // ---- stage c = mask ? es*log2e*prior : -1e30 for all 16 rows ----
  {
    const int srow = t >> 5, cg0 = t & 31;
    const int sw = srow & 7;
    const size_t grow = (bn + i0 + srow) * (size_t)N_;
    const float* pg = prior + grow;
    const int*   mg = mask  + grow;
#pragma unroll
    for (int k = 0; k < 4; k++) {
      const int g = cg0 + 32 * k;
      f32x4 p0 = *(const f32x4*)(pg + g * 8), p1 = *(const f32x4*)(pg + g * 8 + 4);
      i32x4 m0 = *(const i32x4*)(mg + g * 8), m1 = *(const i32x4*)(mg + g * 8 + 4);
      *(bf16x8*)(&cbuf[srow * 1024 + (g ^ sw) * 8]) = cvtCE(p0, p1, m0, m1, es);
    }
  }

  const float el = el_t[h * BN_ + bn + i0 + lr];
  const float* erp = er_t + h * BN_ + bn + lk * 8;
  const short* hW  = hA + (size_t)(b * 8 + h) * 65536 + l * 8;
  const short* cbl = cbuf + lr * 1024;
  const int xsw = lr & 7;

  bf16x8 hC[4], hN[4];
#pragma unroll
  for (int ff = 0; ff < 4; ff++) hC[ff] = *(const bf16x8*)(hW + ff * 512);

  __syncthreads();

  bf16x8 cC = *(const bf16x8*)(cbl + (lk ^ xsw) * 8);   // s=0: group = 0*4+lk
  f32x4 acc[4] = {};
  f32x4 accS = {};
  bf16x8 ones;
#pragma unroll
  for (int e = 0; e < 8; e++) ones[e] = (short)0x3F80;

  for (int s = 0; s < 32; ++s) {
    const int sn = (s < 31) ? s + 1 : 31;
    const short* hs = hW + (size_t)sn * 2048;          // prefetch next h frags
    hN[0] = *(const bf16x8*)(hs);
    hN[1] = *(const bf16x8*)(hs + 512);
    hN[2] = *(const bf16x8*)(hs + 1024);
    hN[3] = *(const bf16x8*)(hs + 1536);
    bf16x8 cN = *(const bf16x8*)(cbl + (((sn * 4 + lk) ^ xsw) * 8));  // prefetch next c
    f32x4 er0 = *(const f32x4*)(erp + s * 32);
    f32x4 er1 = *(const f32x4*)(erp + s * 32 + 4);

    bf16x8 pf;
#pragma unroll
    for (int q = 0; q < 4; q++) {
      // LR(s)+c = 0.4*|s| + (0.6*s + c)   (leaky-relu as 2 fma, abs is free mod)
      float sA = el + er0[q];
      float vA = fmaf(0.6f, sA, bf2f(cC[q]));
      vA = fmaf(0.4f, fabsf(sA), vA);
      float sB = el + er1[q];
      float vB = fmaf(0.6f, sB, bf2f(cC[q + 4]));
      vB = fmaf(0.4f, fabsf(sB), vB);
      float x1, x2;
      asm("v_exp_f32 %0, %1" : "=v"(x1) : "v"(vA));    // 2^x (log2e pre-folded)
      asm("v_exp_f32 %0, %1" : "=v"(x2) : "v"(vB));
      pf[q] = f2bf(x1); pf[q + 4] = f2bf(x2);
    }
    accS   = __builtin_amdgcn_mfma_f32_16x16x32_bf16(ones, pf, accS, 0, 0, 0);
    acc[0] = __builtin_amdgcn_mfma_f32_16x16x32_bf16(hC[0], pf, acc[0], 0, 0, 0);
    acc[1] = __builtin_amdgcn_mfma_f32_16x16x32_bf16(hC[1], pf, acc[1], 0, 0, 0);
    acc[2] = __builtin_amdgcn_mfma_f32_16x16x32_bf16(hC[2], pf, acc[2], 0, 0, 0);
    acc[3] = __builtin_amdgcn_mfma_f32_16x16x32_bf16(hC[3], pf, acc[3], 0, 0, 0);
#pragma unroll
    for (int ff = 0; ff < 4; ff++) hC[ff] = hN[ff];
    cC = cN;
  }

  const float inv = 1.0f / accS[0];
  const size_t row = bn + i0 + lr;
#pragma unroll
  for (int ff = 0; ff < 4; ff++) {
    f32x4 v = acc[ff];
    v[0] *= inv; v[1] *= inv; v[2] *= inv; v[3] *= inv;
    *(f32x4*)(out + row * HF_ + h * 64 + ff * 16 + lk * 4) = v;
  }
}

extern "C" void kernel_launch(void* const* d_in, const int* in_sizes, int n_in,
                              void* d_out, int out_size, void* d_ws, size_t ws_size,
                              hipStream_t stream) {
  const float* x     = (const float*)d_in[0];
  const int*   adj   = (const int*)  d_in[1];
  const float* prior = (const float*)d_in[2];
  const float* W     = (const float*)d_in[3];
  const float* aL    = (const float*)d_in[4];
  const float* aR    = (const float*)d_in[5];
  const float* es    = (const float*)d_in[6];
  float* out = (float*)d_out;

  char* ws = (char*)d_ws;
  short* hA   = (short*)ws;                                 //  8 MB
  short* xb   = (short*)(ws + 8u  * 1024 * 1024);           //  4 MB
  short* Wt   = (short*)(ws + 12u * 1024 * 1024);           // 256 KB
  float* el_t = (float*)(ws + 12u * 1024 * 1024 + 262144);  // 256 KB
  float* er_t = (float*)(ws + 12u * 1024 * 1024 + 524288);  // 256 KB

  hipLaunchKernelGGL(k_cvt, dim3(1536), dim3(256), 0, stream, x, W, xb, Wt);
  hipLaunchKernelGGL(k_h,   dim3(128, 8), dim3(256), 0, stream,
                     Wt, xb, aL, aR, hA, el_t, er_t);
  hipLaunchKernelGGL(k_attn, dim3(512), dim3(512), 0, stream,
                     hA, el_t, er_t, prior, adj, es, out);
}

// Round 6
// 68.842 us; speedup vs baseline: 2.2636x; 1.0276x over previous
//
#include <hip/hip_runtime.h>
#include <hip/hip_bf16.h>

#define B_ 8
#define N_ 1024
#define FIN_ 256
#define H_ 8
#define F_ 64
#define HF_ 512
#define BN_ 8192
#define LOG2E 1.4426950408889634f

using bf16x8 = __attribute__((ext_vector_type(8))) short;
using f32x4  = __attribute__((ext_vector_type(4))) float;
using i32x4  = __attribute__((ext_vector_type(4))) int;

__device__ __forceinline__ short f2bf(float x) {
  __hip_bfloat16 b = __float2bfloat16(x);
  return *reinterpret_cast<short*>(&b);
}
__device__ __forceinline__ float bf2f(short s) {
  union { unsigned u; float f; } v;
  v.u = ((unsigned)(unsigned short)s) << 16;
  return v.f;
}
__device__ __forceinline__ bf16x8 cvtCE(f32x4 pa, f32x4 pb, i32x4 ma, i32x4 mb, float es) {
  bf16x8 o;
#pragma unroll
  for (int e = 0; e < 4; e++) {
    o[e]     = f2bf(ma[e] != 0 ? es * pa[e] : -1e30f);
    o[e + 4] = f2bf(mb[e] != 0 ? es * pb[e] : -1e30f);
  }
  return o;
}

// K0: xb = bf16(x) (blocks 0..1023); Wt[f][c] = bf16(W[c][f]) (blocks 1024..1535)
__global__ __launch_bounds__(256) void k_cvt(
    const float* __restrict__ x, const float* __restrict__ W,
    short* __restrict__ xb, short* __restrict__ Wt) {
  const int bid = blockIdx.x;
  if (bid < 1024) {
    const int idx = (bid * 256 + threadIdx.x) * 8;
    f32x4 a = *(const f32x4*)(x + idx);
    f32x4 b = *(const f32x4*)(x + idx + 4);
    bf16x8 o;
    o[0]=f2bf(a[0]); o[1]=f2bf(a[1]); o[2]=f2bf(a[2]); o[3]=f2bf(a[3]);
    o[4]=f2bf(b[0]); o[5]=f2bf(b[1]); o[6]=f2bf(b[2]); o[7]=f2bf(b[3]);
    *(bf16x8*)(xb + idx) = o;
  } else {
    const int idx = (bid - 1024) * 256 + threadIdx.x;
    const int f = idx >> 8, c = idx & 255;
    Wt[f * FIN_ + c] = f2bf(W[c * HF_ + f]);
  }
}

// K1: h = x@W per-head 64f x 64n tile, fused el/er epilogue; writes hA in
// MFMA-A-fragment order via LDS transpose:
// hA[((b8h*32+js)*4+ff)*512 + l*8 + e] = h[h*64+ff*16+(l&15)][js*32+(l>>4)*8+e] (j local to b)
__global__ __launch_bounds__(256) void k_h(
    const short* __restrict__ Wt, const short* __restrict__ xb,
    const float* __restrict__ aL, const float* __restrict__ aR,
    short* __restrict__ hA, float* __restrict__ el_t, float* __restrict__ er_t) {
  const int nt = blockIdx.x;
  const int h  = blockIdx.y;
  const int w  = threadIdx.x >> 6;
  const int l  = threadIdx.x & 63;
  const int lr = l & 15, lk = l >> 4;
  const int n0 = nt * 64;
  const int fbase = h * 64 + w * 16;

  f32x4 acc[4] = {};
  const short* arow = Wt + (fbase + lr) * FIN_ + lk * 8;

#pragma unroll
  for (int k0 = 0; k0 < FIN_; k0 += 32) {
    bf16x8 a = *(const bf16x8*)(arow + k0);
#pragma unroll
    for (int nf = 0; nf < 4; nf++) {
      bf16x8 bb = *(const bf16x8*)(xb + (size_t)(n0 + nf * 16 + lr) * FIN_ + k0 + lk * 8);
      acc[nf] = __builtin_amdgcn_mfma_f32_16x16x32_bf16(a, bb, acc[nf], 0, 0, 0);
    }
  }

  __shared__ short sT[64][72];
  __shared__ float sEl[4][64], sEr[4][64];
  float al[4], ar[4];
#pragma unroll
  for (int r = 0; r < 4; r++) {
    const int fl = w * 16 + lk * 4 + r;
    al[r] = aL[h * F_ + fl];
    ar[r] = aR[h * F_ + fl];
  }
#pragma unroll
  for (int nf = 0; nf < 4; nf++) {
    const int nl = nf * 16 + lr;
#pragma unroll
    for (int r = 0; r < 4; r++)
      sT[w * 16 + lk * 4 + r][nl] = f2bf(acc[nf][r]);
    float pl = acc[nf][0]*al[0] + acc[nf][1]*al[1] + acc[nf][2]*al[2] + acc[nf][3]*al[3];
    float pr = acc[nf][0]*ar[0] + acc[nf][1]*ar[1] + acc[nf][2]*ar[2] + acc[nf][3]*ar[3];
    pl += __shfl_xor(pl, 16); pl += __shfl_xor(pl, 32);
    pr += __shfl_xor(pr, 16); pr += __shfl_xor(pr, 32);
    if (lk == 0) { sEl[w][nl] = pl; sEr[w][nl] = pr; }
  }
  __syncthreads();
  if (threadIdx.x < 64) {
    const int n = threadIdx.x;
    el_t[h * BN_ + n0 + n] = (sEl[0][n] + sEl[1][n] + sEl[2][n] + sEl[3][n]) * LOG2E;
    er_t[h * BN_ + n0 + n] = (sEr[0][n] + sEr[1][n] + sEr[2][n] + sEr[3][n]) * LOG2E;
  }
  const int b8h = (nt >> 4) * 8 + h;
  const int jb  = (nt & 15) * 2;
#pragma unroll
  for (int gi = 0; gi < 2; gi++) {
    const int g   = threadIdx.x * 2 + gi;
    const int jsl = g >> 8, ff = (g >> 6) & 3, gl = g & 63;
    const int glr = gl & 15, glk = gl >> 4;
    bf16x8 v = *(const bf16x8*)(&sT[ff * 16 + glr][jsl * 32 + glk * 8]);
    *(bf16x8*)(hA + (((size_t)b8h * 32 + jb + jsl) * 4 + ff) * 512 + gl * 8) = v;
  }
}

// K2: fused attention. Block = 256 thr (4 heads), grid = it*16 + hp*8 + b (b -> XCD).
// Full 16-row c tile in 32KB LDS (one barrier), then 32 j-steps hand-unrolled x2
// with depth-1 prefetch of h, c, AND er. No-max softmax, ones-MFMA denominator.
#define PREF_(sn, Hd, Cd, E0d, E1d)                                   \
  {                                                                   \
    const short* hs_ = hW + (size_t)(sn) * 2048;                      \
    Hd[0] = *(const bf16x8*)(hs_);                                    \
    Hd[1] = *(const bf16x8*)(hs_ + 512);                              \
    Hd[2] = *(const bf16x8*)(hs_ + 1024);                             \
    Hd[3] = *(const bf16x8*)(hs_ + 1536);                             \
    Cd    = *(const bf16x8*)(cbl + (((sn) * 4 + lk) ^ xsw) * 8);      \
    E0d   = *(const f32x4*)(erp + (sn) * 32);                         \
    E1d   = *(const f32x4*)(erp + (sn) * 32 + 4);                     \
  }

#define COMP_(Hu, Cu, E0u, E1u)                                               \
  {                                                                           \
    bf16x8 pf;                                                                \
    _Pragma("unroll")                                                         \
    for (int q = 0; q < 4; q++) {                                             \
      float sA = el + E0u[q];                                                 \
      float vA = fmaf(0.6f, sA, bf2f(Cu[q]));                                 \
      vA = fmaf(0.4f, fabsf(sA), vA);                                         \
      float sB = el + E1u[q];                                                 \
      float vB = fmaf(0.6f, sB, bf2f(Cu[q + 4]));                             \
      vB = fmaf(0.4f, fabsf(sB), vB);                                         \
      float x1_, x2_;                                                         \
      asm("v_exp_f32 %0, %1" : "=v"(x1_) : "v"(vA));                          \
      asm("v_exp_f32 %0, %1" : "=v"(x2_) : "v"(vB));                          \
      pf[q] = f2bf(x1_); pf[q + 4] = f2bf(x2_);                               \
    }                                                                         \
    accS   = __builtin_amdgcn_mfma_f32_16x16x32_bf16(ones, pf, accS, 0, 0, 0);\
    acc[0] = __builtin_amdgcn_mfma_f32_16x16x32_bf16(Hu[0], pf, acc[0], 0,0,0);\
    acc[1] = __builtin_amdgcn_mfma_f32_16x16x32_bf16(Hu[1], pf, acc[1], 0,0,0);\
    acc[2] = __builtin_amdgcn_mfma_f32_16x16x32_bf16(Hu[2], pf, acc[2], 0,0,0);\
    acc[3] = __builtin_amdgcn_mfma_f32_16x16x32_bf16(Hu[3], pf, acc[3], 0,0,0);\
  }

__global__ __launch_bounds__(256, 4) void k_attn(
    const short* __restrict__ hA, const float* __restrict__ el_t,
    const float* __restrict__ er_t, const float* __restrict__ prior,
    const int* __restrict__ mask, const float* __restrict__ esp,
    float* __restrict__ out) {
  const int bid = blockIdx.x;
  const int b  = bid & 7;           // XCD = bid % 8
  const int hp = (bid >> 3) & 1;    // head pair: twin block shares b -> L2-hit c
  const int it = bid >> 4;          // 0..63
  const int t  = threadIdx.x;       // 256 threads = 4 waves
  const int h  = hp * 4 + (t >> 6);
  const int l  = t & 63;
  const int lr = l & 15, lk = l >> 4;
  const int i0 = it * 16;
  const size_t bn = (size_t)b * N_;
  const float es = esp[0] * LOG2E;

  __shared__ short cbuf[16 * 1024];   // 32 KB, XOR-swizzled 16B groups

  // ---- stage c = mask ? es*log2e*prior : -1e30 (16 rows x 1024) ----
  {
    const int srow = t >> 4;          // 0..15
    const int cg0  = t & 15;
    const int sw   = srow & 7;
    const size_t grow = (bn + i0 + srow) * (size_t)N_;
    const float* pg = prior + grow;
    const int*   mg = mask  + grow;
#pragma unroll
    for (int k = 0; k < 8; k++) {
      const int g = cg0 + 16 * k;
      f32x4 p0 = *(const f32x4*)(pg + g * 8), p1 = *(const f32x4*)(pg + g * 8 + 4);
      i32x4 m0 = *(const i32x4*)(mg + g * 8), m1 = *(const i32x4*)(mg + g * 8 + 4);
      *(bf16x8*)(&cbuf[srow * 1024 + (g ^ sw) * 8]) = cvtCE(p0, p1, m0, m1, es);
    }
  }

  const float el = el_t[h * BN_ + bn + i0 + lr];
  const float* erp = er_t + h * BN_ + bn + lk * 8;
  const short* hW  = hA + (size_t)(b * 8 + h) * 65536 + l * 8;
  const short* cbl = cbuf + lr * 1024;
  const int xsw = lr & 7;

  bf16x8 hA_[4], hB_[4], cA_, cB_;
  f32x4 eA0, eA1, eB0, eB1;

  // prefetch s=0: h and er are global (issue before barrier)
  hA_[0] = *(const bf16x8*)(hW);
  hA_[1] = *(const bf16x8*)(hW + 512);
  hA_[2] = *(const bf16x8*)(hW + 1024);
  hA_[3] = *(const bf16x8*)(hW + 1536);
  eA0 = *(const f32x4*)(erp);
  eA1 = *(const f32x4*)(erp + 4);

  f32x4 acc[4] = {};
  f32x4 accS = {};
  bf16x8 ones;
#pragma unroll
  for (int e = 0; e < 8; e++) ones[e] = (short)0x3F80;

  __syncthreads();
  cA_ = *(const bf16x8*)(cbl + ((lk ^ xsw) * 8));

  for (int s = 0; s < 32; s += 2) {
    PREF_(s + 1, hB_, cB_, eB0, eB1);
    COMP_(hA_, cA_, eA0, eA1);
    const int s2 = (s + 2 < 32) ? s + 2 : 31;   // clamp: avoid OOB prefetch
    PREF_(s2, hA_, cA_, eA0, eA1);
    COMP_(hB_, cB_, eB0, eB1);
  }

  const float inv = 1.0f / accS[0];
  const size_t row = bn + i0 + lr;
#pragma unroll
  for (int ff = 0; ff < 4; ff++) {
    f32x4 v = acc[ff];
    v[0] *= inv; v[1] *= inv; v[2] *= inv; v[3] *= inv;
    *(f32x4*)(out + row * HF_ + h * 64 + ff * 16 + lk * 4) = v;
  }
}

extern "C" void kernel_launch(void* const* d_in, const int* in_sizes, int n_in,
                              void* d_out, int out_size, void* d_ws, size_t ws_size,
                              hipStream_t stream) {
  const float* x     = (const float*)d_in[0];
  const int*   adj   = (const int*)  d_in[1];
  const float* prior = (const float*)d_in[2];
  const float* W     = (const float*)d_in[3];
  const float* aL    = (const float*)d_in[4];
  const float* aR    = (const float*)d_in[5];
  const float* es    = (const float*)d_in[6];
  float* out = (float*)d_out;

  char* ws = (char*)d_ws;
  short* hA   = (short*)ws;                                 //  8 MB
  short* xb   = (short*)(ws + 8u  * 1024 * 1024);           //  4 MB
  short* Wt   = (short*)(ws + 12u * 1024 * 1024);           // 256 KB
  float* el_t = (float*)(ws + 12u * 1024 * 1024 + 262144);  // 256 KB
  float* er_t = (float*)(ws + 12u * 1024 * 1024 + 524288);  // 256 KB

  hipLaunchKernelGGL(k_cvt, dim3(1536), dim3(256), 0, stream, x, W, xb, Wt);
  hipLaunchKernelGGL(k_h,   dim3(128, 8), dim3(256), 0, stream,
                     Wt, xb, aL, aR, hA, el_t, er_t);
  hipLaunchKernelGGL(k_attn, dim3(1024), dim3(256), 0, stream,
                     hA, el_t, er_t, prior, adj, es, out);
}

// Round 7
// 65.825 us; speedup vs baseline: 2.3673x; 1.0458x over previous
//
#include <hip/hip_runtime.h>
#include <hip/hip_bf16.h>

#define B_ 8
#define N_ 1024
#define FIN_ 256
#define H_ 8
#define F_ 64
#define HF_ 512
#define BN_ 8192
#define LOG2E 1.4426950408889634f

using bf16x8 = __attribute__((ext_vector_type(8))) short;
using f32x4  = __attribute__((ext_vector_type(4))) float;
using i32x4  = __attribute__((ext_vector_type(4))) int;

__device__ __forceinline__ short f2bf(float x) {
  __hip_bfloat16 b = __float2bfloat16(x);
  return *reinterpret_cast<short*>(&b);
}
__device__ __forceinline__ float bf2f(short s) {
  union { unsigned u; float f; } v;
  v.u = ((unsigned)(unsigned short)s) << 16;
  return v.f;
}
__device__ __forceinline__ bf16x8 cvtCE(f32x4 pa, f32x4 pb, i32x4 ma, i32x4 mb, float es) {
  bf16x8 o;
#pragma unroll
  for (int e = 0; e < 4; e++) {
    o[e]     = f2bf(ma[e] != 0 ? es * pa[e] : -1e30f);
    o[e + 4] = f2bf(mb[e] != 0 ? es * pb[e] : -1e30f);
  }
  return o;
}

// K0: xb = bf16(x) (blocks 0..1023); Wt[f][c] = bf16(W[c][f]) (blocks 1024..1535)
__global__ __launch_bounds__(256) void k_cvt(
    const float* __restrict__ x, const float* __restrict__ W,
    short* __restrict__ xb, short* __restrict__ Wt) {
  const int bid = blockIdx.x;
  if (bid < 1024) {
    const int idx = (bid * 256 + threadIdx.x) * 8;
    f32x4 a = *(const f32x4*)(x + idx);
    f32x4 b = *(const f32x4*)(x + idx + 4);
    bf16x8 o;
    o[0]=f2bf(a[0]); o[1]=f2bf(a[1]); o[2]=f2bf(a[2]); o[3]=f2bf(a[3]);
    o[4]=f2bf(b[0]); o[5]=f2bf(b[1]); o[6]=f2bf(b[2]); o[7]=f2bf(b[3]);
    *(bf16x8*)(xb + idx) = o;
  } else {
    const int idx = (bid - 1024) * 256 + threadIdx.x;
    const int f = idx >> 8, c = idx & 255;
    Wt[f * FIN_ + c] = f2bf(W[c * HF_ + f]);
  }
}

// K1: h = x@W per-head 64f x 64n tile, fused el/er epilogue; writes hA in
// MFMA-A-fragment order via LDS transpose:
// hAg[((b8h*32+js)*4+ff)*512 + l*8 + e] = h[h*64+ff*16+(l&15)][js*32+(l>>4)*8+e] (j local to b)
__global__ __launch_bounds__(256) void k_h(
    const short* __restrict__ Wt, const short* __restrict__ xb,
    const float* __restrict__ aL, const float* __restrict__ aR,
    short* __restrict__ hAg, float* __restrict__ el_t, float* __restrict__ er_t) {
  const int nt = blockIdx.x;
  const int h  = blockIdx.y;
  const int w  = threadIdx.x >> 6;
  const int l  = threadIdx.x & 63;
  const int lr = l & 15, lk = l >> 4;
  const int n0 = nt * 64;
  const int fbase = h * 64 + w * 16;

  f32x4 acc[4] = {};
  const short* arow = Wt + (fbase + lr) * FIN_ + lk * 8;

#pragma unroll
  for (int k0 = 0; k0 < FIN_; k0 += 32) {
    bf16x8 a = *(const bf16x8*)(arow + k0);
#pragma unroll
    for (int nf = 0; nf < 4; nf++) {
      bf16x8 bb = *(const bf16x8*)(xb + (size_t)(n0 + nf * 16 + lr) * FIN_ + k0 + lk * 8);
      acc[nf] = __builtin_amdgcn_mfma_f32_16x16x32_bf16(a, bb, acc[nf], 0, 0, 0);
    }
  }

  __shared__ short sT[64][72];
  __shared__ float sEl[4][64], sEr[4][64];
  float al[4], ar[4];
#pragma unroll
  for (int r = 0; r < 4; r++) {
    const int fl = w * 16 + lk * 4 + r;
    al[r] = aL[h * F_ + fl];
    ar[r] = aR[h * F_ + fl];
  }
#pragma unroll
  for (int nf = 0; nf < 4; nf++) {
    const int nl = nf * 16 + lr;
#pragma unroll
    for (int r = 0; r < 4; r++)
      sT[w * 16 + lk * 4 + r][nl] = f2bf(acc[nf][r]);
    float pl = acc[nf][0]*al[0] + acc[nf][1]*al[1] + acc[nf][2]*al[2] + acc[nf][3]*al[3];
    float pr = acc[nf][0]*ar[0] + acc[nf][1]*ar[1] + acc[nf][2]*ar[2] + acc[nf][3]*ar[3];
    pl += __shfl_xor(pl, 16); pl += __shfl_xor(pl, 32);
    pr += __shfl_xor(pr, 16); pr += __shfl_xor(pr, 32);
    if (lk == 0) { sEl[w][nl] = pl; sEr[w][nl] = pr; }
  }
  __syncthreads();
  if (threadIdx.x < 64) {
    const int n = threadIdx.x;
    el_t[h * BN_ + n0 + n] = (sEl[0][n] + sEl[1][n] + sEl[2][n] + sEl[3][n]) * LOG2E;
    er_t[h * BN_ + n0 + n] = (sEr[0][n] + sEr[1][n] + sEr[2][n] + sEr[3][n]) * LOG2E;
  }
  const int b8h = (nt >> 4) * 8 + h;
  const int jb  = (nt & 15) * 2;
#pragma unroll
  for (int gi = 0; gi < 2; gi++) {
    const int g   = threadIdx.x * 2 + gi;
    const int jsl = g >> 8, ff = (g >> 6) & 3, gl = g & 63;
    const int glr = gl & 15, glk = gl >> 4;
    bf16x8 v = *(const bf16x8*)(&sT[ff * 16 + glr][jsl * 32 + glk * 8]);
    *(bf16x8*)(hAg + (((size_t)b8h * 32 + jb + jsl) * 4 + ff) * 512 + gl * 8) = v;
  }
}

// K2: fused attention. Block = 256 thr (4 heads), 32-row i-tile (2 i-frags per
// wave sharing every h/er load -> L2 h-traffic halved, 2x VALU per load for
// latency cover). Grid = it*16 + hp*8 + b (b -> XCD), 512 blocks = 2/CU.
// Full 32-row c tile in 66KB LDS, one barrier, branchless 2-set pipeline.
#define PREF_G(sn, Hd, E0d, E1d)                                      \
  {                                                                   \
    const short* hs_ = hW + (size_t)(sn) * 2048;                      \
    Hd[0] = *(const bf16x8*)(hs_);                                    \
    Hd[1] = *(const bf16x8*)(hs_ + 512);                              \
    Hd[2] = *(const bf16x8*)(hs_ + 1024);                             \
    Hd[3] = *(const bf16x8*)(hs_ + 1536);                             \
    E0d   = *(const f32x4*)(erp + (sn) * 32);                         \
    E1d   = *(const f32x4*)(erp + (sn) * 32 + 4);                     \
  }

#define PREF_C(sn, C0d, C1d)                                          \
  {                                                                   \
    const int gi_ = (((sn) * 4 + lk) ^ xsw) * 8;                      \
    C0d = *(const bf16x8*)(cbl0 + gi_);                               \
    C1d = *(const bf16x8*)(cbl1 + gi_);                               \
  }

#define COMP2(Hu, C0u, C1u, E0u, E1u)                                          \
  {                                                                            \
    bf16x8 pfA, pfB;                                                           \
    _Pragma("unroll")                                                          \
    for (int q = 0; q < 4; q++) {                                              \
      const float e0 = E0u[q], e1 = E1u[q];                                    \
      float sA  = el0 + e0, sA2 = el0 + e1;                                    \
      float sB  = el1 + e0, sB2 = el1 + e1;                                    \
      float vA  = fmaf(0.6f, sA,  bf2f(C0u[q]));                               \
      vA  = fmaf(0.4f, fabsf(sA),  vA);                                        \
      float vA2 = fmaf(0.6f, sA2, bf2f(C0u[q + 4]));                           \
      vA2 = fmaf(0.4f, fabsf(sA2), vA2);                                       \
      float vB  = fmaf(0.6f, sB,  bf2f(C1u[q]));                               \
      vB  = fmaf(0.4f, fabsf(sB),  vB);                                        \
      float vB2 = fmaf(0.6f, sB2, bf2f(C1u[q + 4]));                           \
      vB2 = fmaf(0.4f, fabsf(sB2), vB2);                                       \
      float x1_, x2_, x3_, x4_;                                                \
      asm("v_exp_f32 %0, %1" : "=v"(x1_) : "v"(vA));                           \
      asm("v_exp_f32 %0, %1" : "=v"(x2_) : "v"(vA2));                          \
      asm("v_exp_f32 %0, %1" : "=v"(x3_) : "v"(vB));                           \
      asm("v_exp_f32 %0, %1" : "=v"(x4_) : "v"(vB2));                          \
      pfA[q] = f2bf(x1_); pfA[q + 4] = f2bf(x2_);                              \
      pfB[q] = f2bf(x3_); pfB[q + 4] = f2bf(x4_);                              \
    }                                                                          \
    accSA   = __builtin_amdgcn_mfma_f32_16x16x32_bf16(ones, pfA, accSA, 0,0,0);\
    accSB   = __builtin_amdgcn_mfma_f32_16x16x32_bf16(ones, pfB, accSB, 0,0,0);\
    accA[0] = __builtin_amdgcn_mfma_f32_16x16x32_bf16(Hu[0], pfA, accA[0],0,0,0);\
    accB[0] = __builtin_amdgcn_mfma_f32_16x16x32_bf16(Hu[0], pfB, accB[0],0,0,0);\
    accA[1] = __builtin_amdgcn_mfma_f32_16x16x32_bf16(Hu[1], pfA, accA[1],0,0,0);\
    accB[1] = __builtin_amdgcn_mfma_f32_16x16x32_bf16(Hu[1], pfB, accB[1],0,0,0);\
    accA[2] = __builtin_amdgcn_mfma_f32_16x16x32_bf16(Hu[2], pfA, accA[2],0,0,0);\
    accB[2] = __builtin_amdgcn_mfma_f32_16x16x32_bf16(Hu[2], pfB, accB[2],0,0,0);\
    accA[3] = __builtin_amdgcn_mfma_f32_16x16x32_bf16(Hu[3], pfA, accA[3],0,0,0);\
    accB[3] = __builtin_amdgcn_mfma_f32_16x16x32_bf16(Hu[3], pfB, accB[3],0,0,0);\
  }

__global__ __launch_bounds__(256, 2) void k_attn(
    const short* __restrict__ hAg, const float* __restrict__ el_t,
    const float* __restrict__ er_t, const float* __restrict__ prior,
    const int* __restrict__ mask, const float* __restrict__ esp,
    float* __restrict__ out) {
  const int bid = blockIdx.x;
  const int b  = bid & 7;           // XCD = bid % 8
  const int hp = (bid >> 3) & 1;    // head pair
  const int it = bid >> 4;          // 0..31
  const int t  = threadIdx.x;       // 256 threads = 4 waves
  const int h  = hp * 4 + (t >> 6);
  const int l  = t & 63;
  const int lr = l & 15, lk = l >> 4;
  const int i0 = it * 32;
  const size_t bn = (size_t)b * N_;
  const float es = esp[0] * LOG2E;

  __shared__ short cbuf[33 * 1024];   // 32 rows x 1024 + pad (branchless prefetch)

  // ---- stage c = mask ? es*log2e*prior : -1e30 (32 rows x 1024, swizzled) ----
  {
    const int srow = t >> 3;          // 0..31
    const int g0   = t & 7;
    const int sw   = srow & 7;
    const size_t grow = (bn + i0 + srow) * (size_t)N_;
    const float* pg = prior + grow;
    const int*   mg = mask  + grow;
#pragma unroll
    for (int k = 0; k < 16; k++) {
      const int g = g0 + 8 * k;
      f32x4 p0 = *(const f32x4*)(pg + g * 8), p1 = *(const f32x4*)(pg + g * 8 + 4);
      i32x4 m0 = *(const i32x4*)(mg + g * 8), m1 = *(const i32x4*)(mg + g * 8 + 4);
      *(bf16x8*)(&cbuf[srow * 1024 + (g ^ sw) * 8]) = cvtCE(p0, p1, m0, m1, es);
    }
  }

  const float el0 = el_t[h * BN_ + bn + i0 + lr];
  const float el1 = el_t[h * BN_ + bn + i0 + 16 + lr];
  const float* erp = er_t + h * BN_ + bn + lk * 8;
  const short* hW  = hAg + (size_t)(b * 8 + h) * 65536 + l * 8;
  const short* cbl0 = cbuf + lr * 1024;
  const short* cbl1 = cbuf + (16 + lr) * 1024;
  const int xsw = lr & 7;

  bf16x8 HA[4], HB[4], cA0, cA1, cB0, cB1;
  f32x4 eA0, eA1, eB0, eB1;

  PREF_G(0, HA, eA0, eA1);            // global prefetch before barrier
  PREF_G(1, HB, eB0, eB1);

  f32x4 accA[4] = {}, accB[4] = {};
  f32x4 accSA = {}, accSB = {};
  bf16x8 ones;
#pragma unroll
  for (int e = 0; e < 8; e++) ones[e] = (short)0x3F80;

  __syncthreads();
  PREF_C(0, cA0, cA1);
  PREF_C(1, cB0, cB1);

  for (int s = 0; s < 32; s += 2) {   // branchless: tail prefetches hit padding
    COMP2(HA, cA0, cA1, eA0, eA1);
    PREF_G(s + 2, HA, eA0, eA1);
    PREF_C(s + 2, cA0, cA1);
    COMP2(HB, cB0, cB1, eB0, eB1);
    PREF_G(s + 3, HB, eB0, eB1);
    PREF_C(s + 3, cB0, cB1);
  }

  const float invA = 1.0f / accSA[0];
  const float invB = 1.0f / accSB[0];
  const size_t rowA = bn + i0 + lr;
  const size_t rowB = rowA + 16;
#pragma unroll
  for (int ff = 0; ff < 4; ff++) {
    f32x4 va = accA[ff], vb = accB[ff];
    va[0]*=invA; va[1]*=invA; va[2]*=invA; va[3]*=invA;
    vb[0]*=invB; vb[1]*=invB; vb[2]*=invB; vb[3]*=invB;
    *(f32x4*)(out + rowA * HF_ + h * 64 + ff * 16 + lk * 4) = va;
    *(f32x4*)(out + rowB * HF_ + h * 64 + ff * 16 + lk * 4) = vb;
  }
}

extern "C" void kernel_launch(void* const* d_in, const int* in_sizes, int n_in,
                              void* d_out, int out_size, void* d_ws, size_t ws_size,
                              hipStream_t stream) {
  const float* x     = (const float*)d_in[0];
  const int*   adj   = (const int*)  d_in[1];
  const float* prior = (const float*)d_in[2];
  const float* W     = (const float*)d_in[3];
  const float* aL    = (const float*)d_in[4];
  const float* aR    = (const float*)d_in[5];
  const float* es    = (const float*)d_in[6];
  float* out = (float*)d_out;

  char* ws = (char*)d_ws;
  short* hAg  = (short*)ws;                                 //  8 MB
  short* xb   = (short*)(ws + 8u  * 1024 * 1024);           //  4 MB
  short* Wt   = (short*)(ws + 12u * 1024 * 1024);           // 256 KB
  float* el_t = (float*)(ws + 12u * 1024 * 1024 + 262144);  // 256 KB
  float* er_t = (float*)(ws + 12u * 1024 * 1024 + 524288);  // 256 KB

  hipLaunchKernelGGL(k_cvt, dim3(1536), dim3(256), 0, stream, x, W, xb, Wt);
  hipLaunchKernelGGL(k_h,   dim3(128, 8), dim3(256), 0, stream,
                     Wt, xb, aL, aR, hAg, el_t, er_t);
  hipLaunchKernelGGL(k_attn, dim3(512), dim3(256), 0, stream,
                     hAg, el_t, er_t, prior, adj, es, out);
}

// Round 8
// 63.783 us; speedup vs baseline: 2.4431x; 1.0320x over previous
//
#include <hip/hip_runtime.h>
#include <hip/hip_bf16.h>

#define B_ 8
#define N_ 1024
#define FIN_ 256
#define H_ 8
#define F_ 64
#define HF_ 512
#define BN_ 8192
#define LOG2E 1.4426950408889634f

using bf16x8 = __attribute__((ext_vector_type(8))) short;
using f32x4  = __attribute__((ext_vector_type(4))) float;
using i32x4  = __attribute__((ext_vector_type(4))) int;

__device__ __forceinline__ short f2bf(float x) {
  __hip_bfloat16 b = __float2bfloat16(x);
  return *reinterpret_cast<short*>(&b);
}
__device__ __forceinline__ float bf2f(short s) {
  union { unsigned u; float f; } v;
  v.u = ((unsigned)(unsigned short)s) << 16;
  return v.f;
}
__device__ __forceinline__ bf16x8 cvtCE(f32x4 pa, f32x4 pb, i32x4 ma, i32x4 mb, float es) {
  bf16x8 o;
#pragma unroll
  for (int e = 0; e < 4; e++) {
    o[e]     = f2bf(ma[e] != 0 ? es * pa[e] : -1e30f);
    o[e + 4] = f2bf(mb[e] != 0 ? es * pb[e] : -1e30f);
  }
  return o;
}

// K0: xb = bf16(x) (blocks 0..1023); Wt[f][c] = bf16(W[c][f]) (blocks 1024..1535)
__global__ __launch_bounds__(256) void k_cvt(
    const float* __restrict__ x, const float* __restrict__ W,
    short* __restrict__ xb, short* __restrict__ Wt) {
  const int bid = blockIdx.x;
  if (bid < 1024) {
    const int idx = (bid * 256 + threadIdx.x) * 8;
    f32x4 a = *(const f32x4*)(x + idx);
    f32x4 b = *(const f32x4*)(x + idx + 4);
    bf16x8 o;
    o[0]=f2bf(a[0]); o[1]=f2bf(a[1]); o[2]=f2bf(a[2]); o[3]=f2bf(a[3]);
    o[4]=f2bf(b[0]); o[5]=f2bf(b[1]); o[6]=f2bf(b[2]); o[7]=f2bf(b[3]);
    *(bf16x8*)(xb + idx) = o;
  } else {
    const int idx = (bid - 1024) * 256 + threadIdx.x;
    const int f = idx >> 8, c = idx & 255;
    Wt[f * FIN_ + c] = f2bf(W[c * HF_ + f]);
  }
}

// K1: h = x@W per-head 64f x 64n tile, fused el/er epilogue; writes hA in
// MFMA-A-fragment order via LDS transpose:
// hAg[((b8h*32+js)*4+ff)*512 + l*8 + e] = h[h*64+ff*16+(l&15)][js*32+(l>>4)*8+e] (j local to b)
__global__ __launch_bounds__(256) void k_h(
    const short* __restrict__ Wt, const short* __restrict__ xb,
    const float* __restrict__ aL, const float* __restrict__ aR,
    short* __restrict__ hAg, float* __restrict__ el_t, float* __restrict__ er_t) {
  const int nt = blockIdx.x;
  const int h  = blockIdx.y;
  const int w  = threadIdx.x >> 6;
  const int l  = threadIdx.x & 63;
  const int lr = l & 15, lk = l >> 4;
  const int n0 = nt * 64;
  const int fbase = h * 64 + w * 16;

  f32x4 acc[4] = {};
  const short* arow = Wt + (fbase + lr) * FIN_ + lk * 8;

#pragma unroll
  for (int k0 = 0; k0 < FIN_; k0 += 32) {
    bf16x8 a = *(const bf16x8*)(arow + k0);
#pragma unroll
    for (int nf = 0; nf < 4; nf++) {
      bf16x8 bb = *(const bf16x8*)(xb + (size_t)(n0 + nf * 16 + lr) * FIN_ + k0 + lk * 8);
      acc[nf] = __builtin_amdgcn_mfma_f32_16x16x32_bf16(a, bb, acc[nf], 0, 0, 0);
    }
  }

  __shared__ short sT[64][72];
  __shared__ float sEl[4][64], sEr[4][64];
  float al[4], ar[4];
#pragma unroll
  for (int r = 0; r < 4; r++) {
    const int fl = w * 16 + lk * 4 + r;
    al[r] = aL[h * F_ + fl];
    ar[r] = aR[h * F_ + fl];
  }
#pragma unroll
  for (int nf = 0; nf < 4; nf++) {
    const int nl = nf * 16 + lr;
#pragma unroll
    for (int r = 0; r < 4; r++)
      sT[w * 16 + lk * 4 + r][nl] = f2bf(acc[nf][r]);
    float pl = acc[nf][0]*al[0] + acc[nf][1]*al[1] + acc[nf][2]*al[2] + acc[nf][3]*al[3];
    float pr = acc[nf][0]*ar[0] + acc[nf][1]*ar[1] + acc[nf][2]*ar[2] + acc[nf][3]*ar[3];
    pl += __shfl_xor(pl, 16); pl += __shfl_xor(pl, 32);
    pr += __shfl_xor(pr, 16); pr += __shfl_xor(pr, 32);
    if (lk == 0) { sEl[w][nl] = pl; sEr[w][nl] = pr; }
  }
  __syncthreads();
  if (threadIdx.x < 64) {
    const int n = threadIdx.x;
    el_t[h * BN_ + n0 + n] = (sEl[0][n] + sEl[1][n] + sEl[2][n] + sEl[3][n]) * LOG2E;
    er_t[h * BN_ + n0 + n] = (sEr[0][n] + sEr[1][n] + sEr[2][n] + sEr[3][n]) * LOG2E;
  }
  const int b8h = (nt >> 4) * 8 + h;
  const int jb  = (nt & 15) * 2;
#pragma unroll
  for (int gi = 0; gi < 2; gi++) {
    const int g   = threadIdx.x * 2 + gi;
    const int jsl = g >> 8, ff = (g >> 6) & 3, gl = g & 63;
    const int glr = gl & 15, glk = gl >> 4;
    bf16x8 v = *(const bf16x8*)(&sT[ff * 16 + glr][jsl * 32 + glk * 8]);
    *(bf16x8*)(hAg + (((size_t)b8h * 32 + jb + jsl) * 4 + ff) * 512 + gl * 8) = v;
  }
}

// K2: fused attention. Same structure as R7 (32-row i-tile, 2 i-frags/wave,
// 4 heads/block, 66KB c-tile LDS, one barrier) BUT with sched_barrier(0)
// fences pinning the depth-2 software pipeline (compiler was sinking the
// prefetches to their uses -> exposed L2 latency; VGPR=88 was the tell),
// and s_setprio around the MFMA cluster.
#define PREF_G(sn, Hd, E0d, E1d)                                      \
  {                                                                   \
    const short* hs_ = hW + (size_t)(sn) * 2048;                      \
    Hd[0] = *(const bf16x8*)(hs_);                                    \
    Hd[1] = *(const bf16x8*)(hs_ + 512);                              \
    Hd[2] = *(const bf16x8*)(hs_ + 1024);                             \
    Hd[3] = *(const bf16x8*)(hs_ + 1536);                             \
    E0d   = *(const f32x4*)(erp + (sn) * 32);                         \
    E1d   = *(const f32x4*)(erp + (sn) * 32 + 4);                     \
  }

#define PREF_C(sn, C0d, C1d)                                          \
  {                                                                   \
    const int gi_ = (((sn) * 4 + lk) ^ xsw) * 8;                      \
    C0d = *(const bf16x8*)(cbl0 + gi_);                               \
    C1d = *(const bf16x8*)(cbl1 + gi_);                               \
  }

#define COMP2(Hu, C0u, C1u, E0u, E1u)                                          \
  {                                                                            \
    bf16x8 pfA, pfB;                                                           \
    _Pragma("unroll")                                                          \
    for (int q = 0; q < 4; q++) {                                              \
      const float e0 = E0u[q], e1 = E1u[q];                                    \
      float sA  = el0 + e0, sA2 = el0 + e1;                                    \
      float sB  = el1 + e0, sB2 = el1 + e1;                                    \
      float vA  = fmaf(0.6f, sA,  bf2f(C0u[q]));                               \
      vA  = fmaf(0.4f, fabsf(sA),  vA);                                        \
      float vA2 = fmaf(0.6f, sA2, bf2f(C0u[q + 4]));                           \
      vA2 = fmaf(0.4f, fabsf(sA2), vA2);                                       \
      float vB  = fmaf(0.6f, sB,  bf2f(C1u[q]));                               \
      vB  = fmaf(0.4f, fabsf(sB),  vB);                                        \
      float vB2 = fmaf(0.6f, sB2, bf2f(C1u[q + 4]));                           \
      vB2 = fmaf(0.4f, fabsf(sB2), vB2);                                       \
      float x1_, x2_, x3_, x4_;                                                \
      asm("v_exp_f32 %0, %1" : "=v"(x1_) : "v"(vA));                           \
      asm("v_exp_f32 %0, %1" : "=v"(x2_) : "v"(vA2));                          \
      asm("v_exp_f32 %0, %1" : "=v"(x3_) : "v"(vB));                           \
      asm("v_exp_f32 %0, %1" : "=v"(x4_) : "v"(vB2));                          \
      pfA[q] = f2bf(x1_); pfA[q + 4] = f2bf(x2_);                              \
      pfB[q] = f2bf(x3_); pfB[q + 4] = f2bf(x4_);                              \
    }                                                                          \
    __builtin_amdgcn_s_setprio(1);                                             \
    accSA   = __builtin_amdgcn_mfma_f32_16x16x32_bf16(ones, pfA, accSA, 0,0,0);\
    accSB   = __builtin_amdgcn_mfma_f32_16x16x32_bf16(ones, pfB, accSB, 0,0,0);\
    accA[0] = __builtin_amdgcn_mfma_f32_16x16x32_bf16(Hu[0], pfA, accA[0],0,0,0);\
    accB[0] = __builtin_amdgcn_mfma_f32_16x16x32_bf16(Hu[0], pfB, accB[0],0,0,0);\
    accA[1] = __builtin_amdgcn_mfma_f32_16x16x32_bf16(Hu[1], pfA, accA[1],0,0,0);\
    accB[1] = __builtin_amdgcn_mfma_f32_16x16x32_bf16(Hu[1], pfB, accB[1],0,0,0);\
    accA[2] = __builtin_amdgcn_mfma_f32_16x16x32_bf16(Hu[2], pfA, accA[2],0,0,0);\
    accB[2] = __builtin_amdgcn_mfma_f32_16x16x32_bf16(Hu[2], pfB, accB[2],0,0,0);\
    accA[3] = __builtin_amdgcn_mfma_f32_16x16x32_bf16(Hu[3], pfA, accA[3],0,0,0);\
    accB[3] = __builtin_amdgcn_mfma_f32_16x16x32_bf16(Hu[3], pfB, accB[3],0,0,0);\
    __builtin_amdgcn_s_setprio(0);                                             \
  }

__global__ __launch_bounds__(256, 2) void k_attn(
    const short* __restrict__ hAg, const float* __restrict__ el_t,
    const float* __restrict__ er_t, const float* __restrict__ prior,
    const int* __restrict__ mask, const float* __restrict__ esp,
    float* __restrict__ out) {
  const int bid = blockIdx.x;
  const int b  = bid & 7;           // XCD = bid % 8
  const int hp = (bid >> 3) & 1;    // head pair
  const int it = bid >> 4;          // 0..31
  const int t  = threadIdx.x;       // 256 threads = 4 waves
  const int h  = hp * 4 + (t >> 6);
  const int l  = t & 63;
  const int lr = l & 15, lk = l >> 4;
  const int i0 = it * 32;
  const size_t bn = (size_t)b * N_;
  const float es = esp[0] * LOG2E;

  __shared__ short cbuf[33 * 1024];   // 32 rows x 1024 + pad (branchless prefetch)

  // ---- stage c = mask ? es*log2e*prior : -1e30 (32 rows x 1024, swizzled) ----
  {
    const int srow = t >> 3;          // 0..31
    const int g0   = t & 7;
    const int sw   = srow & 7;
    const size_t grow = (bn + i0 + srow) * (size_t)N_;
    const float* pg = prior + grow;
    const int*   mg = mask  + grow;
#pragma unroll
    for (int k = 0; k < 16; k++) {
      const int g = g0 + 8 * k;
      f32x4 p0 = *(const f32x4*)(pg + g * 8), p1 = *(const f32x4*)(pg + g * 8 + 4);
      i32x4 m0 = *(const i32x4*)(mg + g * 8), m1 = *(const i32x4*)(mg + g * 8 + 4);
      *(bf16x8*)(&cbuf[srow * 1024 + (g ^ sw) * 8]) = cvtCE(p0, p1, m0, m1, es);
    }
  }

  const float el0 = el_t[h * BN_ + bn + i0 + lr];
  const float el1 = el_t[h * BN_ + bn + i0 + 16 + lr];
  const float* erp = er_t + h * BN_ + bn + lk * 8;
  const short* hW  = hAg + (size_t)(b * 8 + h) * 65536 + l * 8;
  const short* cbl0 = cbuf + lr * 1024;
  const short* cbl1 = cbuf + (16 + lr) * 1024;
  const int xsw = lr & 7;

  bf16x8 HA[4], HB[4], cA0, cA1, cB0, cB1;
  f32x4 eA0, eA1, eB0, eB1;

  PREF_G(0, HA, eA0, eA1);            // global prefetch before barrier
  PREF_G(1, HB, eB0, eB1);

  f32x4 accA[4] = {}, accB[4] = {};
  f32x4 accSA = {}, accSB = {};
  bf16x8 ones;
#pragma unroll
  for (int e = 0; e < 8; e++) ones[e] = (short)0x3F80;

  __syncthreads();
  PREF_C(0, cA0, cA1);
  PREF_C(1, cB0, cB1);
  __builtin_amdgcn_sched_barrier(0);

  for (int s = 0; s < 32; s += 2) {   // branchless: tail prefetches hit padding
    COMP2(HA, cA0, cA1, eA0, eA1);
    __builtin_amdgcn_sched_barrier(0);   // pin: prefetches may not sink below
    PREF_G(s + 2, HA, eA0, eA1);
    PREF_C(s + 2, cA0, cA1);
    __builtin_amdgcn_sched_barrier(0);   // pin: COMP2(B) may not hoist above
    COMP2(HB, cB0, cB1, eB0, eB1);
    __builtin_amdgcn_sched_barrier(0);
    PREF_G(s + 3, HB, eB0, eB1);
    PREF_C(s + 3, cB0, cB1);
    __builtin_amdgcn_sched_barrier(0);
  }

  const float invA = 1.0f / accSA[0];
  const float invB = 1.0f / accSB[0];
  const size_t rowA = bn + i0 + lr;
  const size_t rowB = rowA + 16;
#pragma unroll
  for (int ff = 0; ff < 4; ff++) {
    f32x4 va = accA[ff], vb = accB[ff];
    va[0]*=invA; va[1]*=invA; va[2]*=invA; va[3]*=invA;
    vb[0]*=invB; vb[1]*=invB; vb[2]*=invB; vb[3]*=invB;
    *(f32x4*)(out + rowA * HF_ + h * 64 + ff * 16 + lk * 4) = va;
    *(f32x4*)(out + rowB * HF_ + h * 64 + ff * 16 + lk * 4) = vb;
  }
}

extern "C" void kernel_launch(void* const* d_in, const int* in_sizes, int n_in,
                              void* d_out, int out_size, void* d_ws, size_t ws_size,
                              hipStream_t stream) {
  const float* x     = (const float*)d_in[0];
  const int*   adj   = (const int*)  d_in[1];
  const float* prior = (const float*)d_in[2];
  const float* W     = (const float*)d_in[3];
  const float* aL    = (const float*)d_in[4];
  const float* aR    = (const float*)d_in[5];
  const float* es    = (const float*)d_in[6];
  float* out = (float*)d_out;

  char* ws = (char*)d_ws;
  short* hAg  = (short*)ws;                                 //  8 MB
  short* xb   = (short*)(ws + 8u  * 1024 * 1024);           //  4 MB
  short* Wt   = (short*)(ws + 12u * 1024 * 1024);           // 256 KB
  float* el_t = (float*)(ws + 12u * 1024 * 1024 + 262144);  // 256 KB
  float* er_t = (float*)(ws + 12u * 1024 * 1024 + 524288);  // 256 KB

  hipLaunchKernelGGL(k_cvt, dim3(1536), dim3(256), 0, stream, x, W, xb, Wt);
  hipLaunchKernelGGL(k_h,   dim3(128, 8), dim3(256), 0, stream,
                     Wt, xb, aL, aR, hAg, el_t, er_t);
  hipLaunchKernelGGL(k_attn, dim3(512), dim3(256), 0, stream,
                     hAg, el_t, er_t, prior, adj, es, out);
}